// Round 1
// baseline (967.980 us; speedup 1.0000x reference)
//
#include <hip/hip_runtime.h>
#include <hip/hip_bf16.h>
#include <stdint.h>

#define HIDDEN 4096
#define FFN    14336
#define MDIM   512
#define G1     224   // FFN / 64
#define G2     64    // HIDDEN / 64

#define BM  128
#define BN  128
#define BK  64
#define LDP 72   // padded LDS leading dim (stride 144 B -> 2-way bank alias, free)

typedef __attribute__((ext_vector_type(8))) short bf16x8;
typedef __attribute__((ext_vector_type(4))) float f32x4;

__device__ __forceinline__ ushort f2bf(float f) {
    uint32_t b = __float_as_uint(f);
    uint32_t r = (b + 0x7fffu + ((b >> 16) & 1u)) >> 16;
    return (ushort)r;
}

// ---------------- prep kernels ----------------

__global__ void cvt_x_kernel(const float* __restrict__ x, ushort* __restrict__ xb) {
    int i = blockIdx.x * blockDim.x + threadIdx.x;   // one float4 per thread
    float4 v = ((const float4*)x)[i];
    ushort4 o = make_ushort4(f2bf(v.x), f2bf(v.y), f2bf(v.z), f2bf(v.w));
    ((ushort4*)xb)[i] = o;
}

// lut[(g*K + k)*4 + c] = bf16((c - z[g,k]) * s[g,k]),  c = 0..3
__global__ void build_lut_kernel(const float* __restrict__ s, const float* __restrict__ z,
                                 ushort* __restrict__ lut, int total) {
    int i = blockIdx.x * blockDim.x + threadIdx.x;
    if (i >= total) return;
    float sv = s[i], zv = z[i];
    ushort4 e = make_ushort4(f2bf((0.f - zv) * sv), f2bf((1.f - zv) * sv),
                             f2bf((2.f - zv) * sv), f2bf((3.f - zv) * sv));
    ((ushort4*)lut)[i] = e;
}

// ---------------- dequant staging helper ----------------
// qp: &qw[row_q][k0+kc] (8 consecutive int32, each low byte = 4 rows' 2-bit codes)
// lut_p: &lut[(gb*K + k0 + kc)*4]; row i adds i*Kst*4 entries.
// Writes rows r0..r0+3, cols kc..kc+7 of sB (bf16).
__device__ __forceinline__ void dequant_rows(const int* __restrict__ qp,
                                             const ushort* __restrict__ lut_p, int Kst,
                                             ushort (*sB)[LDP], int r0, int kc) {
    uint4 wa = *(const uint4*)qp;
    uint4 wb = *(const uint4*)(qp + 4);
    uint32_t w[8] = {wa.x, wa.y, wa.z, wa.w, wb.x, wb.y, wb.z, wb.w};
#pragma unroll
    for (int i = 0; i < 4; ++i) {
        const ulonglong2* lp = (const ulonglong2*)(lut_p + (size_t)i * Kst * 4);
        ulonglong2 L0 = lp[0], L1 = lp[1], L2 = lp[2], L3 = lp[3];
        uint64_t e[8] = {L0.x, L0.y, L1.x, L1.y, L2.x, L2.y, L3.x, L3.y};
        const uint32_t shift = 6u - 2u * i;   // row n%4==i -> shift (3-i)*2
        uint32_t o[4];
#pragma unroll
        for (int j2 = 0; j2 < 4; ++j2) {
            uint32_t c0 = (w[2 * j2]     >> shift) & 3u;
            uint32_t c1 = (w[2 * j2 + 1] >> shift) & 3u;
            uint32_t v0 = (uint32_t)(e[2 * j2]     >> (c0 * 16u)) & 0xffffu;
            uint32_t v1 = (uint32_t)(e[2 * j2 + 1] >> (c1 * 16u)) & 0xffffu;
            o[j2] = v0 | (v1 << 16);
        }
        *(uint4*)&sB[r0 + i][kc] = make_uint4(o[0], o[1], o[2], o[3]);
    }
}

// ---------------- GEMM A: gate/up fused + SwiGLU -> h (bf16) ----------------

__global__ __launch_bounds__(256, 2)
void gemm_gateup(const ushort* __restrict__ xb, const int* __restrict__ qw1,
                 const ushort* __restrict__ lut1, const int* __restrict__ qw3,
                 const ushort* __restrict__ lut3, ushort* __restrict__ hbuf) {
    __shared__ ushort sA[BM][LDP];
    __shared__ ushort sB1[BN][LDP];
    __shared__ ushort sB2[BN][LDP];

    const int tid = threadIdx.x;
    const int nt = blockIdx.x % (FFN / BN);   // 0..111
    const int mt = blockIdx.x / (FFN / BN);   // 0..3
    const int m0 = mt * BM, n0 = nt * BN;

    const int lane = tid & 63, wave = tid >> 6;
    const int wm = (wave >> 1) * 64, wn = (wave & 1) * 64;   // 2x2 wave grid, 64x64 each

    // staging assignments
    const int arow = tid >> 1, acb = (tid & 1) * 32;         // A: 128 rows x 2 half-rows
    const int q = tid >> 3, kc = (tid & 7) * 8;              // B: 32 q-rows x 8 k-chunks
    const int r0 = q * 4;
    const int gb = (n0 + r0) % G1;                           // rows gb..gb+3 (no wrap: mult of 4)

    const ushort* xp  = xb  + (size_t)(m0 + arow) * HIDDEN + acb;
    const int*    qp1 = qw1 + (size_t)(n0 / 4 + q) * HIDDEN + kc;
    const int*    qp3 = qw3 + (size_t)(n0 / 4 + q) * HIDDEN + kc;
    const ushort* lb1 = lut1 + ((size_t)gb * HIDDEN + kc) * 4;
    const ushort* lb3 = lut3 + ((size_t)gb * HIDDEN + kc) * 4;

    f32x4 accG[4][4], accU[4][4];
#pragma unroll
    for (int i = 0; i < 4; ++i)
#pragma unroll
        for (int j = 0; j < 4; ++j) {
            accG[i][j] = (f32x4){0.f, 0.f, 0.f, 0.f};
            accU[i][j] = (f32x4){0.f, 0.f, 0.f, 0.f};
        }

    const int frow = lane & 15, fk = (lane >> 4) * 8;

    for (int k0 = 0; k0 < HIDDEN; k0 += BK) {
        __syncthreads();
        // stage A (bf16 copy)
#pragma unroll
        for (int i = 0; i < 4; ++i) {
            uint4 v = *(const uint4*)(xp + k0 + 8 * i);
            *(uint4*)&sA[arow][acb + 8 * i] = v;
        }
        // stage B1/B2 via LUT dequant
        dequant_rows(qp1 + k0, lb1 + (size_t)k0 * 4, HIDDEN, sB1, r0, kc);
        dequant_rows(qp3 + k0, lb3 + (size_t)k0 * 4, HIDDEN, sB2, r0, kc);
        __syncthreads();

#pragma unroll
        for (int kk = 0; kk < 2; ++kk) {
            const int col = kk * 32 + fk;
            bf16x8 af[4], bg[4], bu[4];
#pragma unroll
            for (int i = 0; i < 4; ++i) af[i] = *(const bf16x8*)&sA[wm + i * 16 + frow][col];
#pragma unroll
            for (int i = 0; i < 4; ++i) bg[i] = *(const bf16x8*)&sB1[wn + i * 16 + frow][col];
#pragma unroll
            for (int i = 0; i < 4; ++i) bu[i] = *(const bf16x8*)&sB2[wn + i * 16 + frow][col];
#pragma unroll
            for (int mi = 0; mi < 4; ++mi)
#pragma unroll
                for (int ni = 0; ni < 4; ++ni) {
                    accG[mi][ni] = __builtin_amdgcn_mfma_f32_16x16x32_bf16(af[mi], bg[ni], accG[mi][ni], 0, 0, 0);
                    accU[mi][ni] = __builtin_amdgcn_mfma_f32_16x16x32_bf16(af[mi], bu[ni], accU[mi][ni], 0, 0, 0);
                }
        }
    }

    // epilogue: h = silu(gate) * up, bf16
    const int rb = (lane >> 4) * 4, cb = lane & 15;
#pragma unroll
    for (int mi = 0; mi < 4; ++mi)
#pragma unroll
        for (int ni = 0; ni < 4; ++ni) {
            f32x4 g = accG[mi][ni], u = accU[mi][ni];
            const int mm = m0 + wm + mi * 16 + rb;
            const int ff = n0 + wn + ni * 16 + cb;
#pragma unroll
            for (int r = 0; r < 4; ++r) {
                float gv = g[r];
                float hv = (gv / (1.0f + __expf(-gv))) * u[r];
                hbuf[(size_t)(mm + r) * FFN + ff] = f2bf(hv);
            }
        }
}

// ---------------- GEMM B: out_partial = h @ w2^T (split-K = 2) ----------------

__global__ __launch_bounds__(256, 2)
void gemm_down(const ushort* __restrict__ hb, const int* __restrict__ qw2,
               const ushort* __restrict__ lut2, float* __restrict__ part) {
    __shared__ ushort sA[BM][LDP];
    __shared__ ushort sB[BN][LDP];

    const int tid = threadIdx.x;
    const int nt = blockIdx.x & 31;           // HIDDEN/128 = 32
    const int mt = (blockIdx.x >> 5) & 3;     // MDIM/128 = 4
    const int sk = blockIdx.x >> 7;           // split-K half
    const int m0 = mt * BM, n0 = nt * BN;
    const int kbeg = sk * (FFN / 2), kend = kbeg + FFN / 2;

    const int lane = tid & 63, wave = tid >> 6;
    const int wm = (wave >> 1) * 64, wn = (wave & 1) * 64;

    const int arow = tid >> 1, acb = (tid & 1) * 32;
    const int q = tid >> 3, kc = (tid & 7) * 8;
    const int r0 = q * 4;
    const int gb = (n0 + r0) & (G2 - 1);      // n0 mult of 128 -> (n%64) = r0&63

    const ushort* xp  = hb  + (size_t)(m0 + arow) * FFN + acb;
    const int*    qp2 = qw2 + (size_t)(n0 / 4 + q) * FFN + kc;
    const ushort* lb2 = lut2 + ((size_t)gb * FFN + kc) * 4;

    f32x4 acc[4][4];
#pragma unroll
    for (int i = 0; i < 4; ++i)
#pragma unroll
        for (int j = 0; j < 4; ++j) acc[i][j] = (f32x4){0.f, 0.f, 0.f, 0.f};

    const int frow = lane & 15, fk = (lane >> 4) * 8;

    for (int k0 = kbeg; k0 < kend; k0 += BK) {
        __syncthreads();
#pragma unroll
        for (int i = 0; i < 4; ++i) {
            uint4 v = *(const uint4*)(xp + k0 + 8 * i);
            *(uint4*)&sA[arow][acb + 8 * i] = v;
        }
        dequant_rows(qp2 + k0, lb2 + (size_t)k0 * 4, FFN, sB, r0, kc);
        __syncthreads();

#pragma unroll
        for (int kk = 0; kk < 2; ++kk) {
            const int col = kk * 32 + fk;
            bf16x8 af[4], bf[4];
#pragma unroll
            for (int i = 0; i < 4; ++i) af[i] = *(const bf16x8*)&sA[wm + i * 16 + frow][col];
#pragma unroll
            for (int i = 0; i < 4; ++i) bf[i] = *(const bf16x8*)&sB[wn + i * 16 + frow][col];
#pragma unroll
            for (int mi = 0; mi < 4; ++mi)
#pragma unroll
                for (int ni = 0; ni < 4; ++ni)
                    acc[mi][ni] = __builtin_amdgcn_mfma_f32_16x16x32_bf16(af[mi], bf[ni], acc[mi][ni], 0, 0, 0);
        }
    }

    float* pp = part + (size_t)sk * MDIM * HIDDEN;
    const int rb = (lane >> 4) * 4, cb = lane & 15;
#pragma unroll
    for (int mi = 0; mi < 4; ++mi)
#pragma unroll
        for (int ni = 0; ni < 4; ++ni) {
            f32x4 a = acc[mi][ni];
            const int mm = m0 + wm + mi * 16 + rb;
            const int nn = n0 + wn + ni * 16 + cb;
#pragma unroll
            for (int r = 0; r < 4; ++r) pp[(size_t)(mm + r) * HIDDEN + nn] = a[r];
        }
}

// ---------------- reduce split-K partials ----------------

__global__ void reduce_out(const float* __restrict__ part, float* __restrict__ out) {
    int i = blockIdx.x * blockDim.x + threadIdx.x;   // one float4 per thread
    float4 a = ((const float4*)part)[i];
    float4 b = ((const float4*)part)[i + (MDIM * HIDDEN / 4)];
    float4 o;
    o.x = a.x + b.x; o.y = a.y + b.y; o.z = a.z + b.z; o.w = a.w + b.w;
    ((float4*)out)[i] = o;
}

// ---------------- launch ----------------

extern "C" void kernel_launch(void* const* d_in, const int* in_sizes, int n_in,
                              void* d_out, int out_size, void* d_ws, size_t ws_size,
                              hipStream_t stream) {
    (void)in_sizes; (void)n_in; (void)out_size; (void)ws_size;

    const float* x  = (const float*)d_in[0];
    const int*  qw1 = (const int*)d_in[1];
    const float* s1 = (const float*)d_in[2];
    const float* z1 = (const float*)d_in[3];
    const int*  qw3 = (const int*)d_in[4];
    const float* s3 = (const float*)d_in[5];
    const float* z3 = (const float*)d_in[6];
    const int*  qw2 = (const int*)d_in[7];
    const float* s2 = (const float*)d_in[8];
    const float* z2 = (const float*)d_in[9];
    float* out = (float*)d_out;

    // workspace layout (all MB-aligned): xb 4MB | lut1 7MB | lut3 7MB | lut2 7MB | h 14MB | part 16MB
    char* ws = (char*)d_ws;
    ushort* xb   = (ushort*)ws;                                 // 512*4096*2       = 4 MiB
    ushort* lut1 = (ushort*)(ws + (size_t)4 * 1024 * 1024);     // 224*4096*4*2     = 7 MiB
    ushort* lut3 = lut1 + (size_t)G1 * HIDDEN * 4;              // 7 MiB
    ushort* lut2 = lut3 + (size_t)G1 * HIDDEN * 4;              // 64*14336*4*2     = 7 MiB
    ushort* hbuf = lut2 + (size_t)G2 * FFN * 4;                 // 512*14336*2      = 14 MiB
    float*  part = (float*)((char*)hbuf + (size_t)MDIM * FFN * 2);  // 2*512*4096*4 = 16 MiB

    cvt_x_kernel<<<(MDIM * HIDDEN / 4) / 256, 256, 0, stream>>>(x, xb);
    build_lut_kernel<<<(G1 * HIDDEN + 255) / 256, 256, 0, stream>>>(s1, z1, lut1, G1 * HIDDEN);
    build_lut_kernel<<<(G1 * HIDDEN + 255) / 256, 256, 0, stream>>>(s3, z3, lut3, G1 * HIDDEN);
    build_lut_kernel<<<(G2 * FFN + 255) / 256, 256, 0, stream>>>(s2, z2, lut2, G2 * FFN);

    gemm_gateup<<<(FFN / BN) * (MDIM / BM), 256, 0, stream>>>(xb, qw1, lut1, qw3, lut3, hbuf);
    gemm_down<<<2 * (MDIM / BM) * (HIDDEN / BN), 256, 0, stream>>>(hbuf, qw2, lut2, part);
    reduce_out<<<(MDIM * HIDDEN / 4) / 256, 256, 0, stream>>>(part, out);
}

// Round 2
// 842.771 us; speedup vs baseline: 1.1486x; 1.1486x over previous
//
#include <hip/hip_runtime.h>
#include <hip/hip_bf16.h>
#include <stdint.h>

#define HIDDEN 4096
#define FFN    14336
#define MDIM   512
#define G1     224   // FFN / 64
#define G2     64    // HIDDEN / 64
#define BK     64

typedef __attribute__((ext_vector_type(8))) short bf16x8;
typedef __attribute__((ext_vector_type(4))) float f32x4;

__device__ __forceinline__ ushort f2bf(float f) {
    uint32_t b = __float_as_uint(f);
    uint32_t r = (b + 0x7fffu + ((b >> 16) & 1u)) >> 16;
    return (ushort)r;
}

// HW packed f32->bf16 (RNE): dst = bf16(lo) | bf16(hi)<<16
__device__ __forceinline__ uint32_t pk2bf(float lo, float hi) {
    uint32_t r;
    asm("v_cvt_pk_bf16_f32 %0, %1, %2" : "=v"(r) : "v"(lo), "v"(hi));
    return r;
}

// ---------------- prep kernels ----------------

__global__ void cvt_x_kernel(const float* __restrict__ x, ushort* __restrict__ xb) {
    int i = blockIdx.x * blockDim.x + threadIdx.x;   // one float4 per thread
    float4 v = ((const float4*)x)[i];
    ushort4 o = make_ushort4(f2bf(v.x), f2bf(v.y), f2bf(v.z), f2bf(v.w));
    ((ushort4*)xb)[i] = o;
}

// szp[g*K + k] = bf16(z*s) | bf16(s) << 16
__global__ void build_sz_kernel(const float* __restrict__ s, const float* __restrict__ z,
                                uint32_t* __restrict__ szp, int total) {
    int i = blockIdx.x * blockDim.x + threadIdx.x;
    if (i >= total) return;
    float sv = s[i], zv = z[i];
    szp[i] = pk2bf(zv * sv, sv);
}

// dequant core: w8 = 8 qw words (8 k's, 4 rows each); s8 = 8 packed sz for row i.
// produces 8 bf16 (4 u32) for row i.
__device__ __forceinline__ void deq_row(const uint32_t* w8, const uint32_t* s8,
                                        uint32_t sh, uint32_t* o) {
#pragma unroll
    for (int j = 0; j < 4; ++j) {
        uint32_t u0 = s8[2 * j], u1 = s8[2 * j + 1];
        float c0 = (float)((w8[2 * j] >> sh) & 3u);
        float c1 = (float)((w8[2 * j + 1] >> sh) & 3u);
        float v0 = fmaf(c0, __uint_as_float(u0 & 0xFFFF0000u), -__uint_as_float(u0 << 16));
        float v1 = fmaf(c1, __uint_as_float(u1 & 0xFFFF0000u), -__uint_as_float(u1 << 16));
        o[j] = pk2bf(v0, v1);
    }
}

// ---------------- GEMM A: gate/up fused + SwiGLU -> h (bf16) ----------------
// BM=128, BN=64, BK=64, 256 threads (4 waves, 2x2 of 64x32), reg-prefetch pipeline.

__global__ __launch_bounds__(256, 2)
void gemm_gateup(const ushort* __restrict__ xb, const int* __restrict__ qw1,
                 const uint32_t* __restrict__ sz1, const int* __restrict__ qw3,
                 const uint32_t* __restrict__ sz3, ushort* __restrict__ hbuf) {
    __shared__ ushort sA[128][72];
    __shared__ ushort sB1[64][72];
    __shared__ ushort sB2[64][72];

    const int tid = threadIdx.x;
    // XCD swizzle: 896 blocks = 8 XCDs x 112; mt fast -> same-n blocks share XCD (qw/sz L2 reuse)
    const int idx = ((blockIdx.x & 7) * 112) + (blockIdx.x >> 3);
    const int mt = idx & 3, nt = idx >> 2;
    const int m0 = mt * 128, n0 = nt * 64;

    const int lane = tid & 63, wave = tid >> 6;
    const int wm = (wave >> 1) * 64, wn = (wave & 1) * 32;

    // A staging: all 256 threads, 64B each
    const int arow = tid >> 1, acb = (tid & 1) * 32;
    const ushort* ap = xb + (size_t)(m0 + arow) * HIDDEN + acb;

    // B staging: threads 0-127 -> B1(gate), 128-255 -> B3(up); 4 rows x 8 k each
    const int bi = tid & 127;
    const int q = bi >> 3, kc = (bi & 7) * 8;
    const int r0 = q * 4;
    const int gb = (n0 + r0) % G1;   // rows gb..gb+3, no wrap (gb mult of 4, max 220)
    const int* qp = (tid < 128 ? qw1 : qw3) + (size_t)(n0 / 4 + q) * HIDDEN + kc;
    const uint32_t* zp = (tid < 128 ? sz1 : sz3) + (size_t)gb * HIDDEN + kc;
    ushort (*sB)[72] = (tid < 128) ? sB1 : sB2;

    f32x4 accG[4][2], accU[4][2];
#pragma unroll
    for (int i = 0; i < 4; ++i)
#pragma unroll
        for (int j = 0; j < 2; ++j) {
            accG[i][j] = (f32x4){0.f, 0.f, 0.f, 0.f};
            accU[i][j] = (f32x4){0.f, 0.f, 0.f, 0.f};
        }

    const int frow = lane & 15, fk = (lane >> 4) * 8;

    uint4 pa[4];   // A prefetch: 64 B
    uint4 pw[2];   // qw prefetch: 32 B
    uint4 pz[8];   // sz prefetch: 4 rows x 32 B

    auto LOADR = [&](int k0) {
#pragma unroll
        for (int i = 0; i < 4; ++i) pa[i] = *(const uint4*)(ap + k0 + 8 * i);
        pw[0] = *(const uint4*)(qp + k0);
        pw[1] = *(const uint4*)(qp + k0 + 4);
#pragma unroll
        for (int i = 0; i < 4; ++i) {
            const uint4* sp = (const uint4*)(zp + (size_t)i * HIDDEN + k0);
            pz[2 * i] = sp[0];
            pz[2 * i + 1] = sp[1];
        }
    };

    auto DEQWRITE = [&]() {
        *(uint4*)&sA[arow][acb]      = pa[0];
        *(uint4*)&sA[arow][acb + 8]  = pa[1];
        *(uint4*)&sA[arow][acb + 16] = pa[2];
        *(uint4*)&sA[arow][acb + 24] = pa[3];
        uint32_t w[8] = {pw[0].x, pw[0].y, pw[0].z, pw[0].w, pw[1].x, pw[1].y, pw[1].z, pw[1].w};
#pragma unroll
        for (int i = 0; i < 4; ++i) {
            uint32_t s8[8] = {pz[2 * i].x, pz[2 * i].y, pz[2 * i].z, pz[2 * i].w,
                              pz[2 * i + 1].x, pz[2 * i + 1].y, pz[2 * i + 1].z, pz[2 * i + 1].w};
            uint32_t o[4];
            deq_row(w, s8, 6u - 2u * (uint32_t)i, o);
            *(uint4*)&sB[r0 + i][kc] = make_uint4(o[0], o[1], o[2], o[3]);
        }
    };

    auto COMPUTE = [&]() {
#pragma unroll
        for (int kk = 0; kk < 2; ++kk) {
            const int col = kk * 32 + fk;
            bf16x8 af[4], bg[2], bu[2];
#pragma unroll
            for (int i = 0; i < 4; ++i) af[i] = *(const bf16x8*)&sA[wm + i * 16 + frow][col];
            bg[0] = *(const bf16x8*)&sB1[wn + frow][col];
            bg[1] = *(const bf16x8*)&sB1[wn + 16 + frow][col];
            bu[0] = *(const bf16x8*)&sB2[wn + frow][col];
            bu[1] = *(const bf16x8*)&sB2[wn + 16 + frow][col];
#pragma unroll
            for (int mi = 0; mi < 4; ++mi)
#pragma unroll
                for (int ni = 0; ni < 2; ++ni) {
                    accG[mi][ni] = __builtin_amdgcn_mfma_f32_16x16x32_bf16(af[mi], bg[ni], accG[mi][ni], 0, 0, 0);
                    accU[mi][ni] = __builtin_amdgcn_mfma_f32_16x16x32_bf16(af[mi], bu[ni], accU[mi][ni], 0, 0, 0);
                }
        }
    };

    LOADR(0);
    DEQWRITE();
    __syncthreads();

    for (int k0 = BK; k0 < HIDDEN; k0 += BK) {
        LOADR(k0);        // issue next tile's loads (latency hides under COMPUTE)
        COMPUTE();
        __syncthreads();  // all LDS readers done
        DEQWRITE();       // waits vmcnt, dequants, writes LDS
        __syncthreads();
    }
    COMPUTE();

    // ---- epilogue: silu(gate)*up -> LDS -> coalesced bf16 stores ----
    __syncthreads();
    ushort* so = (ushort*)sA;   // 128 x 64 tile
    const int rb = (lane >> 4) * 4, cb = lane & 15;
#pragma unroll
    for (int mi = 0; mi < 4; ++mi)
#pragma unroll
        for (int ni = 0; ni < 2; ++ni) {
            f32x4 g = accG[mi][ni], u = accU[mi][ni];
            const int row = wm + mi * 16 + rb;
            const int colx = wn + ni * 16 + cb;
#pragma unroll
            for (int r = 0; r < 4; ++r) {
                float gv = g[r];
                float hv = __fdividef(gv, 1.0f + __expf(-gv)) * u[r];
                so[(row + r) * 64 + colx] = f2bf(hv);
            }
        }
    __syncthreads();
    {
        const int row = tid >> 1, c0 = (tid & 1) * 32;
        ushort* dst = hbuf + (size_t)(m0 + row) * FFN + n0 + c0;
        const ushort* src = so + row * 64 + c0;
#pragma unroll
        for (int i = 0; i < 4; ++i)
            *(uint4*)(dst + 8 * i) = *(const uint4*)(src + 8 * i);
    }
}

// ---------------- GEMM B: out_partial = h @ w2^T (split-K = 2) ----------------

__global__ __launch_bounds__(256, 2)
void gemm_down(const ushort* __restrict__ hb, const int* __restrict__ qw2,
               const uint32_t* __restrict__ sz2, float* __restrict__ part) {
    __shared__ ushort sA[128][72];
    __shared__ ushort sBd[64][72];

    const int tid = threadIdx.x;
    // 512 blocks = 8 XCDs x 64; mt fast
    const int idx = ((blockIdx.x & 7) * 64) + (blockIdx.x >> 3);
    const int mt = idx & 3, nt = (idx >> 2) & 63, sk = idx >> 8;
    const int m0 = mt * 128, n0 = nt * 64;
    const int kbeg = sk * (FFN / 2), kend = kbeg + FFN / 2;

    const int lane = tid & 63, wave = tid >> 6;
    const int wm = (wave >> 1) * 64, wn = (wave & 1) * 32;

    const int arow = tid >> 1, acb = (tid & 1) * 32;
    const ushort* ap = hb + (size_t)(m0 + arow) * FFN + acb;

    const int bi = tid & 127;
    const int q = bi >> 3, kc = (bi & 7) * 8;
    const int r0 = q * 4;
    const int gb = r0;   // n0 mult of 64, G2 = 64
    const int* qp = qw2 + (size_t)(n0 / 4 + q) * FFN + kc;
    const uint32_t* zp = sz2 + (size_t)gb * FFN + kc;
    const bool doB = (tid < 128);

    f32x4 acc[4][2];
#pragma unroll
    for (int i = 0; i < 4; ++i)
#pragma unroll
        for (int j = 0; j < 2; ++j) acc[i][j] = (f32x4){0.f, 0.f, 0.f, 0.f};

    const int frow = lane & 15, fk = (lane >> 4) * 8;

    uint4 pa[4];
    uint4 pw[2];
    uint4 pz[8];

    auto LOADR = [&](int k0) {
#pragma unroll
        for (int i = 0; i < 4; ++i) pa[i] = *(const uint4*)(ap + k0 + 8 * i);
        if (doB) {
            pw[0] = *(const uint4*)(qp + k0);
            pw[1] = *(const uint4*)(qp + k0 + 4);
#pragma unroll
            for (int i = 0; i < 4; ++i) {
                const uint4* sp = (const uint4*)(zp + (size_t)i * FFN + k0);
                pz[2 * i] = sp[0];
                pz[2 * i + 1] = sp[1];
            }
        }
    };

    auto DEQWRITE = [&]() {
        *(uint4*)&sA[arow][acb]      = pa[0];
        *(uint4*)&sA[arow][acb + 8]  = pa[1];
        *(uint4*)&sA[arow][acb + 16] = pa[2];
        *(uint4*)&sA[arow][acb + 24] = pa[3];
        if (doB) {
            uint32_t w[8] = {pw[0].x, pw[0].y, pw[0].z, pw[0].w, pw[1].x, pw[1].y, pw[1].z, pw[1].w};
#pragma unroll
            for (int i = 0; i < 4; ++i) {
                uint32_t s8[8] = {pz[2 * i].x, pz[2 * i].y, pz[2 * i].z, pz[2 * i].w,
                                  pz[2 * i + 1].x, pz[2 * i + 1].y, pz[2 * i + 1].z, pz[2 * i + 1].w};
                uint32_t o[4];
                deq_row(w, s8, 6u - 2u * (uint32_t)i, o);
                *(uint4*)&sBd[r0 + i][kc] = make_uint4(o[0], o[1], o[2], o[3]);
            }
        }
    };

    auto COMPUTE = [&]() {
#pragma unroll
        for (int kk = 0; kk < 2; ++kk) {
            const int col = kk * 32 + fk;
            bf16x8 af[4], bf[2];
#pragma unroll
            for (int i = 0; i < 4; ++i) af[i] = *(const bf16x8*)&sA[wm + i * 16 + frow][col];
            bf[0] = *(const bf16x8*)&sBd[wn + frow][col];
            bf[1] = *(const bf16x8*)&sBd[wn + 16 + frow][col];
#pragma unroll
            for (int mi = 0; mi < 4; ++mi)
#pragma unroll
                for (int ni = 0; ni < 2; ++ni)
                    acc[mi][ni] = __builtin_amdgcn_mfma_f32_16x16x32_bf16(af[mi], bf[ni], acc[mi][ni], 0, 0, 0);
        }
    };

    LOADR(kbeg);
    DEQWRITE();
    __syncthreads();

    for (int k0 = kbeg + BK; k0 < kend; k0 += BK) {
        LOADR(k0);
        COMPUTE();
        __syncthreads();
        DEQWRITE();
        __syncthreads();
    }
    COMPUTE();

    float* pp = part + (size_t)sk * MDIM * HIDDEN;
    const int rb = (lane >> 4) * 4, cb = lane & 15;
#pragma unroll
    for (int mi = 0; mi < 4; ++mi)
#pragma unroll
        for (int ni = 0; ni < 2; ++ni) {
            f32x4 a = acc[mi][ni];
            const int mm = m0 + wm + mi * 16 + rb;
            const int nn = n0 + wn + ni * 16 + cb;
#pragma unroll
            for (int r = 0; r < 4; ++r) pp[(size_t)(mm + r) * HIDDEN + nn] = a[r];
        }
}

// ---------------- reduce split-K partials ----------------

__global__ void reduce_out(const float* __restrict__ part, float* __restrict__ out) {
    int i = blockIdx.x * blockDim.x + threadIdx.x;   // one float4 per thread
    const int Q = MDIM * HIDDEN / 4;
    float4 a = ((const float4*)part)[i];
    float4 b = ((const float4*)part)[i + Q];
    float4 o;
    o.x = a.x + b.x; o.y = a.y + b.y; o.z = a.z + b.z; o.w = a.w + b.w;
    ((float4*)out)[i] = o;
}

// ---------------- launch ----------------

extern "C" void kernel_launch(void* const* d_in, const int* in_sizes, int n_in,
                              void* d_out, int out_size, void* d_ws, size_t ws_size,
                              hipStream_t stream) {
    (void)in_sizes; (void)n_in; (void)out_size; (void)ws_size;

    const float* x  = (const float*)d_in[0];
    const int*  qw1 = (const int*)d_in[1];
    const float* s1 = (const float*)d_in[2];
    const float* z1 = (const float*)d_in[3];
    const int*  qw3 = (const int*)d_in[4];
    const float* s3 = (const float*)d_in[5];
    const float* z3 = (const float*)d_in[6];
    const int*  qw2 = (const int*)d_in[7];
    const float* s2 = (const float*)d_in[8];
    const float* z2 = (const float*)d_in[9];
    float* out = (float*)d_out;

    // ws layout (bytes): xb 4.19M | sz1 3.67M | sz3 3.67M | sz2 3.67M | h 14.68M | part 16.78M  (~46.7 MB)
    char* ws = (char*)d_ws;
    ushort*   xb   = (ushort*)ws;
    uint32_t* szp1 = (uint32_t*)(ws + (size_t)MDIM * HIDDEN * 2);
    uint32_t* szp3 = szp1 + (size_t)G1 * HIDDEN;
    uint32_t* szp2 = szp3 + (size_t)G1 * HIDDEN;
    ushort*   hbuf = (ushort*)(szp2 + (size_t)G2 * FFN);
    float*    part = (float*)((char*)hbuf + (size_t)MDIM * FFN * 2);

    cvt_x_kernel<<<(MDIM * HIDDEN / 4) / 256, 256, 0, stream>>>(x, xb);
    build_sz_kernel<<<(G1 * HIDDEN) / 256, 256, 0, stream>>>(s1, z1, szp1, G1 * HIDDEN);
    build_sz_kernel<<<(G1 * HIDDEN) / 256, 256, 0, stream>>>(s3, z3, szp3, G1 * HIDDEN);
    build_sz_kernel<<<(G2 * FFN) / 256, 256, 0, stream>>>(s2, z2, szp2, G2 * FFN);

    gemm_gateup<<<(FFN / 64) * (MDIM / 128), 256, 0, stream>>>(xb, qw1, szp1, qw3, szp3, hbuf);
    gemm_down<<<2 * (MDIM / 128) * (HIDDEN / 64), 256, 0, stream>>>(hbuf, qw2, szp2, part);
    reduce_out<<<(MDIM * HIDDEN / 4) / 256, 256, 0, stream>>>(part, out);
}

// Round 4
// 351.914 us; speedup vs baseline: 2.7506x; 2.3948x over previous
//
#include <hip/hip_runtime.h>
#include <hip/hip_fp16.h>
#include <stdint.h>

#define HIDDEN 4096
#define FFN    14336
#define MDIM   512
#define G1     224   // FFN / 64
#define G2     64    // HIDDEN / 64
#define BK     64

typedef _Float16 f16x8 __attribute__((ext_vector_type(8)));
typedef float f32x4 __attribute__((ext_vector_type(4)));

// async global->LDS, 16B per lane; LDS dest = wave-uniform base + lane*16
__device__ __forceinline__ void gl_lds16(const void* g, void* l) {
    __builtin_amdgcn_global_load_lds(
        (const __attribute__((address_space(1))) uint32_t*)g,
        (__attribute__((address_space(3))) uint32_t*)l, 16, 0, 0);
}

#define SCHED0() __builtin_amdgcn_sched_barrier(0);
#define LGKM_BAR()                                            \
    asm volatile("s_waitcnt lgkmcnt(0)" ::: "memory");        \
    __builtin_amdgcn_s_barrier();                             \
    __builtin_amdgcn_sched_barrier(0);

// ---------------- prep kernels ----------------

__global__ void cvt_x_kernel(const float* __restrict__ x, ushort* __restrict__ xb) {
    int i = blockIdx.x * blockDim.x + threadIdx.x;   // one float4 per thread
    float4 v = ((const float4*)x)[i];
    __half2 a = __floats2half2_rn(v.x, v.y);
    __half2 b = __floats2half2_rn(v.z, v.w);
    ((uint2*)xb)[i] = make_uint2(__builtin_bit_cast(uint32_t, a),
                                 __builtin_bit_cast(uint32_t, b));
}

// out[2i] = {f16(s0), f16(s1)}, out[2i+1] = {f16(-z0*s0), f16(-z1*s1)}  (k-pair interleave)
__global__ void build_sz_kernel(const float* __restrict__ s, const float* __restrict__ z,
                                uint32_t* __restrict__ outp) {
    int i = blockIdx.x * blockDim.x + threadIdx.x;
    float s0 = s[2 * i], s1 = s[2 * i + 1];
    float z0 = z[2 * i], z1 = z[2 * i + 1];
    __half2 hs = __floats2half2_rn(s0, s1);
    __half2 hn = __floats2half2_rn(-z0 * s0, -z1 * s1);
    ((uint2*)outp)[i] = make_uint2(__builtin_bit_cast(uint32_t, hs),
                                   __builtin_bit_cast(uint32_t, hn));
}

// dequant 2 codes -> packed f16 pair: table-select via v_perm + v_pk_fma_f16
__device__ __forceinline__ uint32_t deq2(uint32_t w0, uint32_t w1, uint32_t sh,
                                         uint32_t spair, uint32_t npair) {
    uint32_t c0 = (w0 >> sh) & 3u;
    uint32_t c1 = (w1 >> sh) & 3u;
    uint32_t sel = 0x01000100u + c0 * 0x0202u + c1 * 0x02020000u;
    uint32_t codes = __builtin_amdgcn_perm(0x42004000u, 0x3C000000u, sel); // f16{0,1,2,3}
    __half2 r = __hfma2(__builtin_bit_cast(__half2, codes),
                        __builtin_bit_cast(__half2, spair),
                        __builtin_bit_cast(__half2, npair));
    return __builtin_bit_cast(uint32_t, r);
}

// ---------------- GEMM A: gate/up fused + SwiGLU -> h (f16) ----------------
// BM=128, BN=64, BK=64, 4 waves (2x2 of 64x32). A: global_load_lds dbuf,
// swizzled source. B: reg-staged LUT-free f16 dequant, qw prefetched 2 deep.

__global__ __launch_bounds__(256, 2)
void gemm_gateup(const ushort* __restrict__ xb, const uint32_t* __restrict__ qw1,
                 const uint32_t* __restrict__ sz1, const uint32_t* __restrict__ qw3,
                 const uint32_t* __restrict__ sz3, ushort* __restrict__ hbuf) {
    __shared__ ushort sAl[2][128 * 64];
    __shared__ ushort sB1[64 * 64];
    __shared__ ushort sB2[64 * 64];

    const int tid = threadIdx.x;
    // XCD swizzle: 896 = 8 x 112, mt fast
    const int idx = ((blockIdx.x & 7) * 112) + (blockIdx.x >> 3);
    const int mt = idx & 3, nt = idx >> 2;
    const int m0 = mt * 128, n0 = nt * 64;

    const int lane = tid & 63, w = tid >> 6;
    const int wm = (w >> 1) * 64, wn = (w & 1) * 32;
    const int frow = lane & 15, fk = (lane >> 4) * 8;
    const int sw = (frow & 7) << 3;          // read-side XOR swizzle

    // A gload source (pre-swizzled column chunk so linear LDS + swizzled read works)
    const int qs = (lane & 7) ^ ((lane >> 3) & 7);
    const ushort* apS[4];
#pragma unroll
    for (int s = 0; s < 4; ++s) {
        int r = s * 32 + w * 8 + (lane >> 3);
        apS[s] = xb + (size_t)(m0 + r) * HIDDEN + qs * 8;
    }

    // B staging: threads 0-127 -> gate, 128-255 -> up; 4 rows x 8 k each
    const int bi = tid & 127;
    const int q = bi >> 3, kc = (bi & 7) * 8;
    const int r0 = q * 4;
    const int gb = (n0 + r0) % G1;           // rows gb..gb+3, no wrap
    const uint32_t* qp = (tid < 128 ? qw1 : qw3) + (size_t)(n0 / 4 + q) * HIDDEN + kc;
    const uint32_t* zp = (tid < 128 ? sz1 : sz3) + (size_t)gb * HIDDEN + kc;
    ushort* sB = (tid < 128) ? sB1 : sB2;

    f32x4 accG[4][2], accU[4][2];
#pragma unroll
    for (int i = 0; i < 4; ++i)
#pragma unroll
        for (int j = 0; j < 2; ++j) {
            accG[i][j] = (f32x4){0.f, 0.f, 0.f, 0.f};
            accU[i][j] = (f32x4){0.f, 0.f, 0.f, 0.f};
        }

    uint4 pwA0, pwA1, pwB0, pwB1;                     // qw prefetch, 2 deep
    uint4 pz0, pz1, pz2, pz3, pz4, pz5, pz6, pz7;     // sz prefetch, 1 deep
    int cur = 0;

#define GU_GLDA(k0d, curd)                                                     \
    { _Pragma("unroll")                                                        \
      for (int s = 0; s < 4; ++s)                                              \
          gl_lds16(apS[s] + (k0d), &sAl[curd][(s * 256 + w * 64) * 8]); }

#define GU_LDQW(PQ0, PQ1, k0q)                                                 \
    PQ0 = *(const uint4*)(qp + (k0q));                                         \
    PQ1 = *(const uint4*)(qp + (k0q) + 4);

#define GU_LDSZ(k0z)                                                           \
    pz0 = *(const uint4*)(zp + (k0z));                                         \
    pz1 = *(const uint4*)(zp + (k0z) + 4);                                     \
    pz2 = *(const uint4*)(zp + HIDDEN + (k0z));                                \
    pz3 = *(const uint4*)(zp + HIDDEN + (k0z) + 4);                            \
    pz4 = *(const uint4*)(zp + 2 * HIDDEN + (k0z));                            \
    pz5 = *(const uint4*)(zp + 2 * HIDDEN + (k0z) + 4);                        \
    pz6 = *(const uint4*)(zp + 3 * HIDDEN + (k0z));                            \
    pz7 = *(const uint4*)(zp + 3 * HIDDEN + (k0z) + 4);

#define GU_DEQ(PQ0, PQ1)                                                       \
    { const uint32_t wv[8] = {(PQ0).x, (PQ0).y, (PQ0).z, (PQ0).w,              \
                              (PQ1).x, (PQ1).y, (PQ1).z, (PQ1).w};             \
      const uint4 pzv[8] = {pz0, pz1, pz2, pz3, pz4, pz5, pz6, pz7};           \
      _Pragma("unroll")                                                        \
      for (int i = 0; i < 4; ++i) {                                            \
          const uint32_t sh = 6u - 2u * (uint32_t)i;                           \
          const uint32_t sp[4] = {pzv[2*i].x, pzv[2*i].z, pzv[2*i+1].x, pzv[2*i+1].z}; \
          const uint32_t np[4] = {pzv[2*i].y, pzv[2*i].w, pzv[2*i+1].y, pzv[2*i+1].w}; \
          uint32_t o[4];                                                       \
          _Pragma("unroll")                                                    \
          for (int j = 0; j < 4; ++j)                                          \
              o[j] = deq2(wv[2*j], wv[2*j+1], sh, sp[j], np[j]);               \
          const int row_ = r0 + i;                                             \
          *(uint4*)&sB[row_ * 64 + (kc ^ ((row_ & 7) << 3))] =                 \
              make_uint4(o[0], o[1], o[2], o[3]);                              \
      } }

#define GU_COMP()                                                              \
    { _Pragma("unroll")                                                        \
      for (int kk = 0; kk < 2; ++kk) {                                         \
          const int col = ((kk * 32) + fk) ^ sw;                               \
          f16x8 af[4], bg[2], bu[2];                                           \
          _Pragma("unroll")                                                    \
          for (int i = 0; i < 4; ++i)                                          \
              af[i] = *(const f16x8*)&sAl[cur][(wm + i * 16 + frow) * 64 + col]; \
          bg[0] = *(const f16x8*)&sB1[(wn + frow) * 64 + col];                 \
          bg[1] = *(const f16x8*)&sB1[(wn + 16 + frow) * 64 + col];            \
          bu[0] = *(const f16x8*)&sB2[(wn + frow) * 64 + col];                 \
          bu[1] = *(const f16x8*)&sB2[(wn + 16 + frow) * 64 + col];            \
          _Pragma("unroll")                                                    \
          for (int mi = 0; mi < 4; ++mi)                                       \
              _Pragma("unroll")                                                \
              for (int ni = 0; ni < 2; ++ni) {                                 \
                  accG[mi][ni] = __builtin_amdgcn_mfma_f32_16x16x32_f16(af[mi], bg[ni], accG[mi][ni], 0, 0, 0); \
                  accU[mi][ni] = __builtin_amdgcn_mfma_f32_16x16x32_f16(af[mi], bu[ni], accU[mi][ni], 0, 0, 0); \
              } } }

#define GU_STEP(k0s, PC0, PC1, PN0, PN1, DOPF, VMS)                            \
    { GU_GLDA((k0s) + BK, cur ^ 1) SCHED0()                                    \
      if (DOPF) { GU_LDQW(PN0, PN1, (k0s) + 2 * BK) } SCHED0()                 \
      GU_COMP()                                                                \
      LGKM_BAR()                                                               \
      GU_DEQ(PC0, PC1)                                                         \
      SCHED0()                                                                 \
      asm volatile("s_waitcnt vmcnt(" VMS ")" ::: "memory"); SCHED0()          \
      if (DOPF) { GU_LDSZ((k0s) + 2 * BK) } SCHED0()                           \
      LGKM_BAR()                                                               \
      cur ^= 1; }

    // prologue: tile 0 staged, qw(1)/sz(1) in flight
    GU_GLDA(0, 0)
    GU_LDQW(pwA0, pwA1, 0)
    GU_LDSZ(0)
    asm volatile("s_waitcnt vmcnt(0)" ::: "memory"); SCHED0()
    GU_DEQ(pwA0, pwA1)
    GU_LDQW(pwB0, pwB1, BK)
    GU_LDSZ(BK)
    LGKM_BAR()

    for (int k0 = 0; k0 < 62 * BK; k0 += 2 * BK) {
        GU_STEP(k0, pwB0, pwB1, pwA0, pwA1, 1, "2")
        GU_STEP(k0 + BK, pwA0, pwA1, pwB0, pwB1, 1, "2")
    }
    GU_STEP(62 * BK, pwB0, pwB1, pwA0, pwA1, 0, "0")
    GU_COMP()   // tile 63

    // ---- epilogue: silu(gate)*up -> LDS -> coalesced f16 stores ----
    ushort* so = &sAl[0][0];   // 128 x 64 staging (cur==1 at end; plane 0 is dead)
    const int rb = (lane >> 4) * 4, cb = lane & 15;
#pragma unroll
    for (int mi = 0; mi < 4; ++mi)
#pragma unroll
        for (int ni = 0; ni < 2; ++ni) {
            f32x4 g = accG[mi][ni], u = accU[mi][ni];
            const int row = wm + mi * 16 + rb;
            const int colx = wn + ni * 16 + cb;
#pragma unroll
            for (int r = 0; r < 4; ++r) {
                float gv = g[r];
                float hv = __fdividef(gv, 1.0f + __expf(-gv)) * u[r];
                __half hh = __float2half(hv);
                so[(row + r) * 64 + colx] = __builtin_bit_cast(ushort, hh);
            }
        }
    __syncthreads();
    {
        const int row = tid >> 1, c0 = (tid & 1) * 32;
        ushort* dst = hbuf + (size_t)(m0 + row) * FFN + n0 + c0;
        const ushort* src = so + row * 64 + c0;
#pragma unroll
        for (int i = 0; i < 4; ++i)
            *(uint4*)(dst + 8 * i) = *(const uint4*)(src + 8 * i);
    }
#undef GU_GLDA
#undef GU_LDQW
#undef GU_LDSZ
#undef GU_DEQ
#undef GU_COMP
#undef GU_STEP
}

// ---------------- GEMM B: out_partial = h @ w2^T (split-K = 2) ----------------

__global__ __launch_bounds__(256, 2)
void gemm_down(const ushort* __restrict__ hb, const uint32_t* __restrict__ qw2,
               const uint32_t* __restrict__ sz2, float* __restrict__ part) {
    __shared__ ushort sAl[2][128 * 64];
    __shared__ ushort sBd[64 * 64];

    const int tid = threadIdx.x;
    const int idx = ((blockIdx.x & 7) * 64) + (blockIdx.x >> 3);
    const int mt = idx & 3, nt = (idx >> 2) & 63, sk = idx >> 8;
    const int m0 = mt * 128, n0 = nt * 64;
    const int kbeg = sk * (FFN / 2);

    const int lane = tid & 63, w = tid >> 6;
    const int wm = (w >> 1) * 64, wn = (w & 1) * 32;
    const int frow = lane & 15, fk = (lane >> 4) * 8;
    const int sw = (frow & 7) << 3;

    const int qs = (lane & 7) ^ ((lane >> 3) & 7);
    const ushort* apS[4];
#pragma unroll
    for (int s = 0; s < 4; ++s) {
        int r = s * 32 + w * 8 + (lane >> 3);
        apS[s] = hb + (size_t)(m0 + r) * FFN + kbeg + qs * 8;
    }

    // B staging: all 256 threads, 2 rows x 8 k each
    const int q = tid >> 4;            // 0..15
    const int i2 = (tid >> 3) & 1;     // row pair within q-word
    const int kc = (tid & 7) * 8;
    const int rr0 = q * 4 + i2 * 2;
    const uint32_t* qp = qw2 + (size_t)(n0 / 4 + q) * FFN + kbeg + kc;
    const uint32_t* zp = sz2 + (size_t)rr0 * FFN + kbeg + kc;   // g = row (G2=64)

    f32x4 acc[4][2];
#pragma unroll
    for (int i = 0; i < 4; ++i)
#pragma unroll
        for (int j = 0; j < 2; ++j) acc[i][j] = (f32x4){0.f, 0.f, 0.f, 0.f};

    uint4 pwA0, pwA1, pwB0, pwB1;
    uint4 pz0, pz1, pz2, pz3;
    int cur = 0;
    const uint32_t shb = 6u - 4u * (uint32_t)i2;

#define GD_GLDA(k0d, curd)                                                     \
    { _Pragma("unroll")                                                        \
      for (int s = 0; s < 4; ++s)                                              \
          gl_lds16(apS[s] + (k0d), &sAl[curd][(s * 256 + w * 64) * 8]); }

#define GD_LDQW(PQ0, PQ1, k0q)                                                 \
    PQ0 = *(const uint4*)(qp + (k0q));                                         \
    PQ1 = *(const uint4*)(qp + (k0q) + 4);

#define GD_LDSZ(k0z)                                                           \
    pz0 = *(const uint4*)(zp + (k0z));                                         \
    pz1 = *(const uint4*)(zp + (k0z) + 4);                                     \
    pz2 = *(const uint4*)(zp + FFN + (k0z));                                   \
    pz3 = *(const uint4*)(zp + FFN + (k0z) + 4);

#define GD_DEQ(PQ0, PQ1)                                                       \
    { const uint32_t wv[8] = {(PQ0).x, (PQ0).y, (PQ0).z, (PQ0).w,              \
                              (PQ1).x, (PQ1).y, (PQ1).z, (PQ1).w};             \
      const uint4 pzv[2] = {pz0, pz2};                                         \
      const uint4 pzw[2] = {pz1, pz3};                                         \
      _Pragma("unroll")                                                        \
      for (int ii = 0; ii < 2; ++ii) {                                         \
          const uint32_t sh = shb - 2u * (uint32_t)ii;                         \
          const uint32_t sp[4] = {pzv[ii].x, pzv[ii].z, pzw[ii].x, pzw[ii].z}; \
          const uint32_t np[4] = {pzv[ii].y, pzv[ii].w, pzw[ii].y, pzw[ii].w}; \
          uint32_t o[4];                                                       \
          _Pragma("unroll")                                                    \
          for (int j = 0; j < 4; ++j)                                          \
              o[j] = deq2(wv[2*j], wv[2*j+1], sh, sp[j], np[j]);               \
          const int row_ = rr0 + ii;                                           \
          *(uint4*)&sBd[row_ * 64 + (kc ^ ((row_ & 7) << 3))] =                \
              make_uint4(o[0], o[1], o[2], o[3]);                              \
      } }

#define GD_COMP()                                                              \
    { _Pragma("unroll")                                                        \
      for (int kk = 0; kk < 2; ++kk) {                                         \
          const int col = ((kk * 32) + fk) ^ sw;                               \
          f16x8 af[4], bf[2];                                                  \
          _Pragma("unroll")                                                    \
          for (int i = 0; i < 4; ++i)                                          \
              af[i] = *(const f16x8*)&sAl[cur][(wm + i * 16 + frow) * 64 + col]; \
          bf[0] = *(const f16x8*)&sBd[(wn + frow) * 64 + col];                 \
          bf[1] = *(const f16x8*)&sBd[(wn + 16 + frow) * 64 + col];            \
          _Pragma("unroll")                                                    \
          for (int mi = 0; mi < 4; ++mi)                                       \
              _Pragma("unroll")                                                \
              for (int ni = 0; ni < 2; ++ni)                                   \
                  acc[mi][ni] = __builtin_amdgcn_mfma_f32_16x16x32_f16(af[mi], bf[ni], acc[mi][ni], 0, 0, 0); \
      } }

#define GD_STEP(k0s, PC0, PC1, PN0, PN1, DOPF, VMS)                            \
    { GD_GLDA((k0s) + BK, cur ^ 1) SCHED0()                                    \
      if (DOPF) { GD_LDQW(PN0, PN1, (k0s) + 2 * BK) } SCHED0()                 \
      GD_COMP()                                                                \
      LGKM_BAR()                                                               \
      GD_DEQ(PC0, PC1)                                                         \
      SCHED0()                                                                 \
      asm volatile("s_waitcnt vmcnt(" VMS ")" ::: "memory"); SCHED0()          \
      if (DOPF) { GD_LDSZ((k0s) + 2 * BK) } SCHED0()                           \
      LGKM_BAR()                                                               \
      cur ^= 1; }

    GD_GLDA(0, 0)
    GD_LDQW(pwA0, pwA1, 0)
    GD_LDSZ(0)
    asm volatile("s_waitcnt vmcnt(0)" ::: "memory"); SCHED0()
    GD_DEQ(pwA0, pwA1)
    GD_LDQW(pwB0, pwB1, BK)
    GD_LDSZ(BK)
    LGKM_BAR()

    for (int k0 = 0; k0 < 110 * BK; k0 += 2 * BK) {
        GD_STEP(k0, pwB0, pwB1, pwA0, pwA1, 1, "2")
        GD_STEP(k0 + BK, pwA0, pwA1, pwB0, pwB1, 1, "2")
    }
    GD_STEP(110 * BK, pwB0, pwB1, pwA0, pwA1, 0, "0")
    GD_COMP()   // tile 111

    float* pp = part + (size_t)sk * MDIM * HIDDEN;
    const int rb = (lane >> 4) * 4, cb = lane & 15;
#pragma unroll
    for (int mi = 0; mi < 4; ++mi)
#pragma unroll
        for (int ni = 0; ni < 2; ++ni) {
            f32x4 a = acc[mi][ni];
            const int mm = m0 + wm + mi * 16 + rb;
            const int nn = n0 + wn + ni * 16 + cb;
#pragma unroll
            for (int r = 0; r < 4; ++r) pp[(size_t)(mm + r) * HIDDEN + nn] = a[r];
        }
#undef GD_GLDA
#undef GD_LDQW
#undef GD_LDSZ
#undef GD_DEQ
#undef GD_COMP
#undef GD_STEP
}

// ---------------- reduce split-K partials ----------------

__global__ void reduce_out(const float* __restrict__ part, float* __restrict__ out) {
    int i = blockIdx.x * blockDim.x + threadIdx.x;
    const int Q = MDIM * HIDDEN / 4;
    float4 a = ((const float4*)part)[i];
    float4 b = ((const float4*)part)[i + Q];
    float4 o;
    o.x = a.x + b.x; o.y = a.y + b.y; o.z = a.z + b.z; o.w = a.w + b.w;
    ((float4*)out)[i] = o;
}

// ---------------- launch ----------------

extern "C" void kernel_launch(void* const* d_in, const int* in_sizes, int n_in,
                              void* d_out, int out_size, void* d_ws, size_t ws_size,
                              hipStream_t stream) {
    (void)in_sizes; (void)n_in; (void)out_size; (void)ws_size;

    const float* x  = (const float*)d_in[0];
    const uint32_t* qw1 = (const uint32_t*)d_in[1];
    const float* s1 = (const float*)d_in[2];
    const float* z1 = (const float*)d_in[3];
    const uint32_t* qw3 = (const uint32_t*)d_in[4];
    const float* s3 = (const float*)d_in[5];
    const float* z3 = (const float*)d_in[6];
    const uint32_t* qw2 = (const uint32_t*)d_in[7];
    const float* s2 = (const float*)d_in[8];
    const float* z2 = (const float*)d_in[9];
    float* out = (float*)d_out;

    // ws: xb 4.19M | sz1 3.67M | sz3 3.67M | sz2 3.67M | h(f16) 14.68M | part 16.78M
    char* ws = (char*)d_ws;
    ushort*   xb   = (ushort*)ws;
    uint32_t* szp1 = (uint32_t*)(ws + (size_t)MDIM * HIDDEN * 2);
    uint32_t* szp3 = szp1 + (size_t)G1 * HIDDEN;
    uint32_t* szp2 = szp3 + (size_t)G1 * HIDDEN;
    ushort*   hbuf = (ushort*)(szp2 + (size_t)G2 * FFN);
    float*    part = (float*)((char*)hbuf + (size_t)MDIM * FFN * 2);

    cvt_x_kernel<<<(MDIM * HIDDEN / 4) / 256, 256, 0, stream>>>(x, xb);
    build_sz_kernel<<<(G1 * HIDDEN / 2) / 256, 256, 0, stream>>>(s1, z1, szp1);
    build_sz_kernel<<<(G1 * HIDDEN / 2) / 256, 256, 0, stream>>>(s3, z3, szp3);
    build_sz_kernel<<<(G2 * FFN / 2) / 256, 256, 0, stream>>>(s2, z2, szp2);

    gemm_gateup<<<(FFN / 64) * (MDIM / 128), 256, 0, stream>>>(xb, qw1, szp1, qw3, szp3, hbuf);
    gemm_down<<<2 * (MDIM / 128) * (HIDDEN / 64), 256, 0, stream>>>(hbuf, qw2, szp2, part);
    reduce_out<<<(MDIM * HIDDEN / 4) / 256, 256, 0, stream>>>(part, out);
}

// Round 5
// 350.245 us; speedup vs baseline: 2.7637x; 1.0048x over previous
//
#include <hip/hip_runtime.h>
#include <hip/hip_fp16.h>
#include <stdint.h>

#define HIDDEN 4096
#define FFN    14336
#define MDIM   512
#define G1     224   // FFN / 64
#define G2     64    // HIDDEN / 64
#define BK     64

typedef _Float16 f16x8 __attribute__((ext_vector_type(8)));
typedef float f32x4 __attribute__((ext_vector_type(4)));

// async global->LDS, 16B per lane; LDS dest = wave-uniform base + lane*16
__device__ __forceinline__ void gl_lds16(const void* g, void* l) {
    __builtin_amdgcn_global_load_lds(
        (const __attribute__((address_space(1))) uint32_t*)g,
        (__attribute__((address_space(3))) uint32_t*)l, 16, 0, 0);
}

#define SCHED0() __builtin_amdgcn_sched_barrier(0);
#define LGKM_BAR()                                            \
    asm volatile("s_waitcnt lgkmcnt(0)" ::: "memory");        \
    __builtin_amdgcn_s_barrier();                             \
    __builtin_amdgcn_sched_barrier(0);

// ---------------- prep kernels ----------------

__global__ void cvt_x_kernel(const float* __restrict__ x, ushort* __restrict__ xb) {
    int i = blockIdx.x * blockDim.x + threadIdx.x;   // one float4 per thread
    float4 v = ((const float4*)x)[i];
    __half2 a = __floats2half2_rn(v.x, v.y);
    __half2 b = __floats2half2_rn(v.z, v.w);
    ((uint2*)xb)[i] = make_uint2(__builtin_bit_cast(uint32_t, a),
                                 __builtin_bit_cast(uint32_t, b));
}

// out[2i] = {f16(s0), f16(s1)}, out[2i+1] = {f16(-z0*s0), f16(-z1*s1)}
__global__ void build_sz_kernel(const float* __restrict__ s, const float* __restrict__ z,
                                uint32_t* __restrict__ outp) {
    int i = blockIdx.x * blockDim.x + threadIdx.x;
    float s0 = s[2 * i], s1 = s[2 * i + 1];
    float z0 = z[2 * i], z1 = z[2 * i + 1];
    __half2 hs = __floats2half2_rn(s0, s1);
    __half2 hn = __floats2half2_rn(-z0 * s0, -z1 * s1);
    ((uint2*)outp)[i] = make_uint2(__builtin_bit_cast(uint32_t, hs),
                                   __builtin_bit_cast(uint32_t, hn));
}

// dequant 2 codes -> packed f16 pair: table-select via v_perm + v_pk_fma_f16
__device__ __forceinline__ uint32_t deq2(uint32_t w0, uint32_t w1, uint32_t sh,
                                         uint32_t spair, uint32_t npair) {
    uint32_t c0 = (w0 >> sh) & 3u;
    uint32_t c1 = (w1 >> sh) & 3u;
    uint32_t sel = 0x01000100u + c0 * 0x0202u + c1 * 0x02020000u;
    uint32_t codes = __builtin_amdgcn_perm(0x42004000u, 0x3C000000u, sel); // f16{0,1,2,3}
    __half2 r = __hfma2(__builtin_bit_cast(__half2, codes),
                        __builtin_bit_cast(__half2, spair),
                        __builtin_bit_cast(__half2, npair));
    return __builtin_bit_cast(uint32_t, r);
}

// ---------------- GEMM A: gate/up fused + SwiGLU -> h (f16) ----------------
// BM=256, BN=32, BK=64, 4 waves stacked in M (wave tile 64x32).
// A: global_load_lds dbuf, pre-swizzled source. B: reg-staged f16 dequant.

__global__ __launch_bounds__(256, 2)
void gemm_gateup(const ushort* __restrict__ xb, const uint32_t* __restrict__ qw1,
                 const uint32_t* __restrict__ sz1, const uint32_t* __restrict__ qw3,
                 const uint32_t* __restrict__ sz3, ushort* __restrict__ hbuf) {
    __shared__ ushort sAl[2][256 * 64];   // 2 x 32 KB
    __shared__ ushort sB1[32 * 64];       // 4 KB
    __shared__ ushort sB2[32 * 64];       // 4 KB

    const int tid = threadIdx.x;
    // XCD swizzle: 896 = 8 x 112; mt fast (mt pairs share B inputs in L2)
    const int idx = ((blockIdx.x & 7) * 112) + (blockIdx.x >> 3);
    const int mt = idx & 1, nt = idx >> 1;       // mt 0..1, nt 0..447
    const int m0 = mt * 256, n0 = nt * 32;

    const int lane = tid & 63, w = tid >> 6;
    const int wm = w * 64;                       // wave m-offset; wn = 0
    const int frow = lane & 15, fk = (lane >> 4) * 8;
    const int sw = (frow & 7) << 3;              // read-side XOR swizzle

    // A gload source (pre-swizzled col chunk; linear LDS dest + swizzled read)
    const int qs = (lane & 7) ^ ((lane >> 3) & 7);
    const ushort* apS[8];
#pragma unroll
    for (int s = 0; s < 8; ++s) {
        int r = s * 32 + w * 8 + (lane >> 3);
        apS[s] = xb + (size_t)(m0 + r) * HIDDEN + qs * 8;
    }

    // B staging: threads 0-127 gate, 128-255 up; 2 rows x 8 k each
    const int bi = tid & 127;
    const int rp = bi >> 3;                      // 0..15 row-pair
    const int kc = (bi & 7) * 8;
    const int row0 = rp * 2;
    const int g0 = (n0 + row0) % G1;             // even, <=222; g1 = g0+1 no wrap
    const uint32_t* qp = (tid < 128 ? qw1 : qw3) + (size_t)(n0 / 4 + (rp >> 1)) * HIDDEN + kc;
    const uint32_t* zp = (tid < 128 ? sz1 : sz3) + (size_t)g0 * HIDDEN + kc;
    ushort* sB = (tid < 128) ? sB1 : sB2;
    const uint32_t sh0 = 6u - 4u * (uint32_t)(rp & 1);

    f32x4 accG[4][2], accU[4][2];
#pragma unroll
    for (int i = 0; i < 4; ++i)
#pragma unroll
        for (int j = 0; j < 2; ++j) {
            accG[i][j] = (f32x4){0.f, 0.f, 0.f, 0.f};
            accU[i][j] = (f32x4){0.f, 0.f, 0.f, 0.f};
        }

    uint4 pw0, pw1;                // qw prefetch (8 words)
    uint4 pz0, pz1, pz2, pz3;      // sz prefetch (row0: pz0/pz1, row1: pz2/pz3)
    int cur = 0;

#define GU_GLDA(k0d, curd)                                                     \
    { _Pragma("unroll")                                                        \
      for (int s = 0; s < 8; ++s)                                              \
          gl_lds16(apS[s] + (k0d), &sAl[curd][(s * 256 + w * 64) * 8]); }

#define GU_LD(k0q)                                                             \
    pw0 = *(const uint4*)(qp + (k0q));                                         \
    pw1 = *(const uint4*)(qp + (k0q) + 4);                                     \
    pz0 = *(const uint4*)(zp + (k0q));                                         \
    pz1 = *(const uint4*)(zp + (k0q) + 4);                                     \
    pz2 = *(const uint4*)(zp + HIDDEN + (k0q));                                \
    pz3 = *(const uint4*)(zp + HIDDEN + (k0q) + 4);

#define GU_DEQ()                                                               \
    { const uint32_t wv[8] = {pw0.x, pw0.y, pw0.z, pw0.w,                      \
                              pw1.x, pw1.y, pw1.z, pw1.w};                     \
      {   const uint32_t sp[4] = {pz0.x, pz0.z, pz1.x, pz1.z};                 \
          const uint32_t np[4] = {pz0.y, pz0.w, pz1.y, pz1.w};                 \
          uint32_t o[4];                                                       \
          _Pragma("unroll")                                                    \
          for (int j = 0; j < 4; ++j)                                          \
              o[j] = deq2(wv[2*j], wv[2*j+1], sh0, sp[j], np[j]);              \
          *(uint4*)&sB[row0 * 64 + (kc ^ ((row0 & 7) << 3))] =                 \
              make_uint4(o[0], o[1], o[2], o[3]);                              \
      }                                                                        \
      {   const uint32_t sp[4] = {pz2.x, pz2.z, pz3.x, pz3.z};                 \
          const uint32_t np[4] = {pz2.y, pz2.w, pz3.y, pz3.w};                 \
          uint32_t o[4];                                                       \
          _Pragma("unroll")                                                    \
          for (int j = 0; j < 4; ++j)                                          \
              o[j] = deq2(wv[2*j], wv[2*j+1], sh0 - 2u, sp[j], np[j]);         \
          const int row1 = row0 + 1;                                           \
          *(uint4*)&sB[row1 * 64 + (kc ^ ((row1 & 7) << 3))] =                 \
              make_uint4(o[0], o[1], o[2], o[3]);                              \
      } }

#define GU_COMP()                                                              \
    { _Pragma("unroll")                                                        \
      for (int kk = 0; kk < 2; ++kk) {                                         \
          const int col = ((kk * 32) + fk) ^ sw;                               \
          f16x8 af[4], bg[2], bu[2];                                           \
          _Pragma("unroll")                                                    \
          for (int i = 0; i < 4; ++i)                                          \
              af[i] = *(const f16x8*)&sAl[cur][(wm + i * 16 + frow) * 64 + col]; \
          bg[0] = *(const f16x8*)&sB1[frow * 64 + col];                        \
          bg[1] = *(const f16x8*)&sB1[(16 + frow) * 64 + col];                 \
          bu[0] = *(const f16x8*)&sB2[frow * 64 + col];                        \
          bu[1] = *(const f16x8*)&sB2[(16 + frow) * 64 + col];                 \
          _Pragma("unroll")                                                    \
          for (int mi = 0; mi < 4; ++mi)                                       \
              _Pragma("unroll")                                                \
              for (int ni = 0; ni < 2; ++ni) {                                 \
                  accG[mi][ni] = __builtin_amdgcn_mfma_f32_16x16x32_f16(af[mi], bg[ni], accG[mi][ni], 0, 0, 0); \
                  accU[mi][ni] = __builtin_amdgcn_mfma_f32_16x16x32_f16(af[mi], bu[ni], accU[mi][ni], 0, 0, 0); \
              } } }

    // prologue: stage tile 0, prefetch tile 1 regs
    GU_GLDA(0, 0)
    GU_LD(0)
    asm volatile("s_waitcnt vmcnt(0)" ::: "memory"); SCHED0()
    GU_DEQ()
    GU_LD(BK)
    LGKM_BAR()

    for (int t = 0; t < 62; ++t) {
        const int k0 = t * BK;
        GU_GLDA(k0 + BK, cur ^ 1) SCHED0()
        GU_COMP()
        LGKM_BAR()
        GU_DEQ()
        SCHED0()
        GU_LD(k0 + 2 * BK)
        SCHED0()
        asm volatile("s_waitcnt vmcnt(6)" ::: "memory"); SCHED0()
        LGKM_BAR()
        cur ^= 1;
    }
    // t = 62: no prefetch
    GU_GLDA(63 * BK, cur ^ 1) SCHED0()
    GU_COMP()
    LGKM_BAR()
    GU_DEQ()
    SCHED0()
    asm volatile("s_waitcnt vmcnt(0)" ::: "memory"); SCHED0()
    LGKM_BAR()
    cur ^= 1;
    GU_COMP()   // tile 63 (cur == 1)

    // ---- epilogue: silu(gate)*up -> LDS -> coalesced f16 stores ----
    ushort* so = &sAl[0][0];   // 256 x 32 staging (16 KB; plane 0 is dead)
    const int rb = (lane >> 4) * 4, cb = lane & 15;
#pragma unroll
    for (int mi = 0; mi < 4; ++mi)
#pragma unroll
        for (int ni = 0; ni < 2; ++ni) {
            f32x4 g = accG[mi][ni], u = accU[mi][ni];
            const int row = wm + mi * 16 + rb;
            const int colx = ni * 16 + cb;
#pragma unroll
            for (int r = 0; r < 4; ++r) {
                float gv = g[r];
                float hv = __fdividef(gv, 1.0f + __expf(-gv)) * u[r];
                __half hh = __float2half(hv);
                so[(row + r) * 32 + colx] = __builtin_bit_cast(ushort, hh);
            }
        }
    __syncthreads();
    {
        ushort* dst = hbuf + (size_t)(m0 + tid) * FFN + n0;
        const ushort* src = so + tid * 32;
#pragma unroll
        for (int i = 0; i < 4; ++i)
            *(uint4*)(dst + 8 * i) = *(const uint4*)(src + 8 * i);
    }
#undef GU_GLDA
#undef GU_LD
#undef GU_DEQ
#undef GU_COMP
}

// ---------------- GEMM B: out_partial = h @ w2^T (split-K = 2) ----------------
// BM=256, BN=32, BK=64, 4 waves stacked in M.

__global__ __launch_bounds__(256, 2)
void gemm_down(const ushort* __restrict__ hb, const uint32_t* __restrict__ qw2,
               const uint32_t* __restrict__ sz2, float* __restrict__ part) {
    __shared__ ushort sAl[2][256 * 64];   // 64 KB
    __shared__ ushort sBd[32 * 64];       // 4 KB

    const int tid = threadIdx.x;
    // 512 = 8 x 64 XCD swizzle
    const int idx = ((blockIdx.x & 7) * 64) + (blockIdx.x >> 3);
    const int mt = idx & 1, nt = (idx >> 1) & 127, sk = idx >> 8;
    const int m0 = mt * 256, n0 = nt * 32;
    const int kbeg = sk * (FFN / 2);

    const int lane = tid & 63, w = tid >> 6;
    const int wm = w * 64;
    const int frow = lane & 15, fk = (lane >> 4) * 8;
    const int sw = (frow & 7) << 3;

    const int qs = (lane & 7) ^ ((lane >> 3) & 7);
    const ushort* apS[8];
#pragma unroll
    for (int s = 0; s < 8; ++s) {
        int r = s * 32 + w * 8 + (lane >> 3);
        apS[s] = hb + (size_t)(m0 + r) * FFN + kbeg + qs * 8;
    }

    // B staging: 1 row x 8 k per thread (32 rows x 8 chunks = 256)
    const int r = tid >> 3;                 // 0..31
    const int kc = (tid & 7) * 8;
    const int g = ((nt & 1) * 32) + r;      // (n0 + r) % 64
    const uint32_t* qp = qw2 + (size_t)(n0 / 4 + (r >> 2)) * FFN + kbeg + kc;
    const uint32_t* zp = sz2 + (size_t)g * FFN + kbeg + kc;
    const uint32_t sh = 6u - 2u * (uint32_t)(r & 3);

    f32x4 acc[4][2];
#pragma unroll
    for (int i = 0; i < 4; ++i)
#pragma unroll
        for (int j = 0; j < 2; ++j) acc[i][j] = (f32x4){0.f, 0.f, 0.f, 0.f};

    uint4 pw0, pw1;
    uint4 pz0, pz1;
    int cur = 0;

#define GD_GLDA(k0d, curd)                                                     \
    { _Pragma("unroll")                                                        \
      for (int s = 0; s < 8; ++s)                                              \
          gl_lds16(apS[s] + (k0d), &sAl[curd][(s * 256 + w * 64) * 8]); }

#define GD_LD(k0q)                                                             \
    pw0 = *(const uint4*)(qp + (k0q));                                         \
    pw1 = *(const uint4*)(qp + (k0q) + 4);                                     \
    pz0 = *(const uint4*)(zp + (k0q));                                         \
    pz1 = *(const uint4*)(zp + (k0q) + 4);

#define GD_DEQ()                                                               \
    { const uint32_t wv[8] = {pw0.x, pw0.y, pw0.z, pw0.w,                      \
                              pw1.x, pw1.y, pw1.z, pw1.w};                     \
      const uint32_t sp[4] = {pz0.x, pz0.z, pz1.x, pz1.z};                     \
      const uint32_t np[4] = {pz0.y, pz0.w, pz1.y, pz1.w};                     \
      uint32_t o[4];                                                           \
      _Pragma("unroll")                                                        \
      for (int j = 0; j < 4; ++j)                                              \
          o[j] = deq2(wv[2*j], wv[2*j+1], sh, sp[j], np[j]);                   \
      *(uint4*)&sBd[r * 64 + (kc ^ ((r & 7) << 3))] =                          \
          make_uint4(o[0], o[1], o[2], o[3]); }

#define GD_COMP()                                                              \
    { _Pragma("unroll")                                                        \
      for (int kk = 0; kk < 2; ++kk) {                                         \
          const int col = ((kk * 32) + fk) ^ sw;                               \
          f16x8 af[4], bf[2];                                                  \
          _Pragma("unroll")                                                    \
          for (int i = 0; i < 4; ++i)                                          \
              af[i] = *(const f16x8*)&sAl[cur][(wm + i * 16 + frow) * 64 + col]; \
          bf[0] = *(const f16x8*)&sBd[frow * 64 + col];                        \
          bf[1] = *(const f16x8*)&sBd[(16 + frow) * 64 + col];                 \
          _Pragma("unroll")                                                    \
          for (int mi = 0; mi < 4; ++mi)                                       \
              _Pragma("unroll")                                                \
              for (int ni = 0; ni < 2; ++ni)                                   \
                  acc[mi][ni] = __builtin_amdgcn_mfma_f32_16x16x32_f16(af[mi], bf[ni], acc[mi][ni], 0, 0, 0); \
      } }

    GD_GLDA(0, 0)
    GD_LD(0)
    asm volatile("s_waitcnt vmcnt(0)" ::: "memory"); SCHED0()
    GD_DEQ()
    GD_LD(BK)
    LGKM_BAR()

    for (int t = 0; t < 110; ++t) {
        const int k0 = t * BK;
        GD_GLDA(k0 + BK, cur ^ 1) SCHED0()
        GD_COMP()
        LGKM_BAR()
        GD_DEQ()
        SCHED0()
        GD_LD(k0 + 2 * BK)
        SCHED0()
        asm volatile("s_waitcnt vmcnt(4)" ::: "memory"); SCHED0()
        LGKM_BAR()
        cur ^= 1;
    }
    // t = 110: no prefetch
    GD_GLDA(111 * BK, cur ^ 1) SCHED0()
    GD_COMP()
    LGKM_BAR()
    GD_DEQ()
    SCHED0()
    asm volatile("s_waitcnt vmcnt(0)" ::: "memory"); SCHED0()
    LGKM_BAR()
    cur ^= 1;
    GD_COMP()   // tile 111 (cur == 1)

    float* pp = part + (size_t)sk * MDIM * HIDDEN;
    const int rb = (lane >> 4) * 4, cb = lane & 15;
#pragma unroll
    for (int mi = 0; mi < 4; ++mi)
#pragma unroll
        for (int ni = 0; ni < 2; ++ni) {
            f32x4 a = acc[mi][ni];
            const int mm = m0 + wm + mi * 16 + rb;
            const int nn = n0 + ni * 16 + cb;
#pragma unroll
            for (int rr = 0; rr < 4; ++rr) pp[(size_t)(mm + rr) * HIDDEN + nn] = a[rr];
        }
#undef GD_GLDA
#undef GD_LD
#undef GD_DEQ
#undef GD_COMP
}

// ---------------- reduce split-K partials ----------------

__global__ void reduce_out(const float* __restrict__ part, float* __restrict__ out) {
    int i = blockIdx.x * blockDim.x + threadIdx.x;
    const int Q = MDIM * HIDDEN / 4;
    float4 a = ((const float4*)part)[i];
    float4 b = ((const float4*)part)[i + Q];
    float4 o;
    o.x = a.x + b.x; o.y = a.y + b.y; o.z = a.z + b.z; o.w = a.w + b.w;
    ((float4*)out)[i] = o;
}

// ---------------- launch ----------------

extern "C" void kernel_launch(void* const* d_in, const int* in_sizes, int n_in,
                              void* d_out, int out_size, void* d_ws, size_t ws_size,
                              hipStream_t stream) {
    (void)in_sizes; (void)n_in; (void)out_size; (void)ws_size;

    const float* x  = (const float*)d_in[0];
    const uint32_t* qw1 = (const uint32_t*)d_in[1];
    const float* s1 = (const float*)d_in[2];
    const float* z1 = (const float*)d_in[3];
    const uint32_t* qw3 = (const uint32_t*)d_in[4];
    const float* s3 = (const float*)d_in[5];
    const float* z3 = (const float*)d_in[6];
    const uint32_t* qw2 = (const uint32_t*)d_in[7];
    const float* s2 = (const float*)d_in[8];
    const float* z2 = (const float*)d_in[9];
    float* out = (float*)d_out;

    // ws: xb 4.19M | sz1 3.67M | sz3 3.67M | sz2 3.67M | h(f16) 14.68M | part 16.78M
    char* ws = (char*)d_ws;
    ushort*   xb   = (ushort*)ws;
    uint32_t* szp1 = (uint32_t*)(ws + (size_t)MDIM * HIDDEN * 2);
    uint32_t* szp3 = szp1 + (size_t)G1 * HIDDEN;
    uint32_t* szp2 = szp3 + (size_t)G1 * HIDDEN;
    ushort*   hbuf = (ushort*)(szp2 + (size_t)G2 * FFN);
    float*    part = (float*)((char*)hbuf + (size_t)MDIM * FFN * 2);

    cvt_x_kernel<<<(MDIM * HIDDEN / 4) / 256, 256, 0, stream>>>(x, xb);
    build_sz_kernel<<<(G1 * HIDDEN / 2) / 256, 256, 0, stream>>>(s1, z1, szp1);
    build_sz_kernel<<<(G1 * HIDDEN / 2) / 256, 256, 0, stream>>>(s3, z3, szp3);
    build_sz_kernel<<<(G2 * FFN / 2) / 256, 256, 0, stream>>>(s2, z2, szp2);

    gemm_gateup<<<(FFN / 32) * (MDIM / 256), 256, 0, stream>>>(xb, qw1, szp1, qw3, szp3, hbuf);
    gemm_down<<<2 * (MDIM / 256) * (HIDDEN / 32), 256, 0, stream>>>(hbuf, qw2, szp2, part);
    reduce_out<<<(MDIM * HIDDEN / 4) / 256, 256, 0, stream>>>(part, out);
}

// Round 6
// 335.415 us; speedup vs baseline: 2.8859x; 1.0442x over previous
//
#include <hip/hip_runtime.h>
#include <hip/hip_fp16.h>
#include <stdint.h>

#define HIDDEN 4096
#define FFN    14336
#define MDIM   512
#define G1     224   // FFN / 64
#define G2     64    // HIDDEN / 64
#define BK     64

typedef _Float16 f16x8 __attribute__((ext_vector_type(8)));
typedef float f32x4 __attribute__((ext_vector_type(4)));

// async global->LDS, 16B per lane; LDS dest = wave-uniform base + lane*16
__device__ __forceinline__ void gl_lds16(const void* g, void* l) {
    __builtin_amdgcn_global_load_lds(
        (const __attribute__((address_space(1))) uint32_t*)g,
        (__attribute__((address_space(3))) uint32_t*)l, 16, 0, 0);
}

#define SCHED0() __builtin_amdgcn_sched_barrier(0);

// ---------------- prep kernels ----------------

__global__ void cvt_x_kernel(const float* __restrict__ x, ushort* __restrict__ xb) {
    int i = blockIdx.x * blockDim.x + threadIdx.x;   // one float4 per thread
    float4 v = ((const float4*)x)[i];
    __half2 a = __floats2half2_rn(v.x, v.y);
    __half2 b = __floats2half2_rn(v.z, v.w);
    ((uint2*)xb)[i] = make_uint2(__builtin_bit_cast(uint32_t, a),
                                 __builtin_bit_cast(uint32_t, b));
}

// out[2i] = {f16(s0), f16(s1)}, out[2i+1] = {f16(-z0*s0), f16(-z1*s1)}
__global__ void build_sz_kernel(const float* __restrict__ s, const float* __restrict__ z,
                                uint32_t* __restrict__ outp) {
    int i = blockIdx.x * blockDim.x + threadIdx.x;
    float s0 = s[2 * i], s1 = s[2 * i + 1];
    float z0 = z[2 * i], z1 = z[2 * i + 1];
    __half2 hs = __floats2half2_rn(s0, s1);
    __half2 hn = __floats2half2_rn(-z0 * s0, -z1 * s1);
    ((uint2*)outp)[i] = make_uint2(__builtin_bit_cast(uint32_t, hs),
                                   __builtin_bit_cast(uint32_t, hn));
}

// dequant 2 codes -> packed f16 pair: table-select via v_perm + v_pk_fma_f16
__device__ __forceinline__ uint32_t deq2(uint32_t w0, uint32_t w1, uint32_t sh,
                                         uint32_t spair, uint32_t npair) {
    uint32_t c0 = (w0 >> sh) & 3u;
    uint32_t c1 = (w1 >> sh) & 3u;
    uint32_t sel = 0x01000100u + c0 * 0x0202u + c1 * 0x02020000u;
    uint32_t codes = __builtin_amdgcn_perm(0x42004000u, 0x3C000000u, sel); // f16{0,1,2,3}
    __half2 r = __hfma2(__builtin_bit_cast(__half2, codes),
                        __builtin_bit_cast(__half2, spair),
                        __builtin_bit_cast(__half2, npair));
    return __builtin_bit_cast(uint32_t, r);
}

// ---------------- GEMM A: gate/up fused + SwiGLU -> h (f16) ----------------
// BM=256, BN=32, BK=64, 4 waves stacked in M (wave tile 64x32).
// Single barrier per K-step: {GLDA(t+1) || DEQ(t+1->alt) || LD(t+3) || COMP(t)}.

__global__ __launch_bounds__(256, 2)
void gemm_gateup(const ushort* __restrict__ xb, const uint32_t* __restrict__ qw1,
                 const uint32_t* __restrict__ sz1, const uint32_t* __restrict__ qw3,
                 const uint32_t* __restrict__ sz3, ushort* __restrict__ hbuf) {
    __shared__ ushort sAl[2][256 * 64];   // 64 KB
    __shared__ ushort sB1[2][32 * 64];    // 8 KB
    __shared__ ushort sB2[2][32 * 64];    // 8 KB

    const int tid = threadIdx.x;
    // XCD swizzle: 896 = 8 x 112; mt fast (mt pairs share B inputs in L2)
    const int idx = ((blockIdx.x & 7) * 112) + (blockIdx.x >> 3);
    const int mt = idx & 1, nt = idx >> 1;       // mt 0..1, nt 0..447
    const int m0 = mt * 256, n0 = nt * 32;

    const int lane = tid & 63, w = tid >> 6;
    const int wm = w * 64;                       // wave m-offset
    const int frow = lane & 15, fk = (lane >> 4) * 8;
    const int sw = (frow & 7) << 3;              // read-side XOR swizzle

    // A gload source (pre-swizzled col chunk; linear LDS dest + swizzled read)
    const int qs = (lane & 7) ^ ((lane >> 3) & 7);
    const ushort* apS[8];
#pragma unroll
    for (int s = 0; s < 8; ++s) {
        int r = s * 32 + w * 8 + (lane >> 3);
        apS[s] = xb + (size_t)(m0 + r) * HIDDEN + qs * 8;
    }

    // B staging: threads 0-127 gate, 128-255 up; 2 rows x 8 k each
    const int bi = tid & 127;
    const int rp = bi >> 3;                      // 0..15 row-pair
    const int kc = (bi & 7) * 8;
    const int row0 = rp * 2;
    const int g0 = (n0 + row0) % G1;             // even, <=222; g1 = g0+1 no wrap
    const uint32_t* qp = (tid < 128 ? qw1 : qw3) + (size_t)(n0 / 4 + (rp >> 1)) * HIDDEN + kc;
    const uint32_t* zp = (tid < 128 ? sz1 : sz3) + (size_t)g0 * HIDDEN + kc;
    ushort (*sB)[32 * 64] = (tid < 128) ? sB1 : sB2;
    const uint32_t sh0 = 6u - 4u * (uint32_t)(rp & 1);

    f32x4 accG[4][2], accU[4][2];
#pragma unroll
    for (int i = 0; i < 4; ++i)
#pragma unroll
        for (int j = 0; j < 2; ++j) {
            accG[i][j] = (f32x4){0.f, 0.f, 0.f, 0.f};
            accU[i][j] = (f32x4){0.f, 0.f, 0.f, 0.f};
        }

    uint4 pwA0, pwA1, pzA0, pzA1, pzA2, pzA3;   // set A
    uint4 pwB0, pwB1, pzB0, pzB1, pzB2, pzB3;   // set B

#define GU_GLDA(k0d, wbuf)                                                     \
    { _Pragma("unroll")                                                        \
      for (int s = 0; s < 8; ++s)                                              \
          gl_lds16(apS[s] + (k0d), &sAl[wbuf][(s * 256 + w * 64) * 8]); }

#define GU_LD(PW0, PW1, PZ0, PZ1, PZ2, PZ3, k0q)                               \
    PW0 = *(const uint4*)(qp + (k0q));                                         \
    PW1 = *(const uint4*)(qp + (k0q) + 4);                                     \
    PZ0 = *(const uint4*)(zp + (k0q));                                         \
    PZ1 = *(const uint4*)(zp + (k0q) + 4);                                     \
    PZ2 = *(const uint4*)(zp + HIDDEN + (k0q));                                \
    PZ3 = *(const uint4*)(zp + HIDDEN + (k0q) + 4);

#define GU_DEQ(wbuf, PW0, PW1, PZ0, PZ1, PZ2, PZ3)                             \
    { const uint32_t wv[8] = {(PW0).x, (PW0).y, (PW0).z, (PW0).w,              \
                              (PW1).x, (PW1).y, (PW1).z, (PW1).w};             \
      {   const uint32_t sp[4] = {(PZ0).x, (PZ0).z, (PZ1).x, (PZ1).z};         \
          const uint32_t np[4] = {(PZ0).y, (PZ0).w, (PZ1).y, (PZ1).w};         \
          uint32_t o[4];                                                       \
          _Pragma("unroll")                                                    \
          for (int j = 0; j < 4; ++j)                                          \
              o[j] = deq2(wv[2*j], wv[2*j+1], sh0, sp[j], np[j]);              \
          *(uint4*)&sB[wbuf][row0 * 64 + (kc ^ ((row0 & 7) << 3))] =           \
              make_uint4(o[0], o[1], o[2], o[3]);                              \
      }                                                                        \
      {   const uint32_t sp[4] = {(PZ2).x, (PZ2).z, (PZ3).x, (PZ3).z};         \
          const uint32_t np[4] = {(PZ2).y, (PZ2).w, (PZ3).y, (PZ3).w};         \
          uint32_t o[4];                                                       \
          _Pragma("unroll")                                                    \
          for (int j = 0; j < 4; ++j)                                          \
              o[j] = deq2(wv[2*j], wv[2*j+1], sh0 - 2u, sp[j], np[j]);         \
          const int row1 = row0 + 1;                                           \
          *(uint4*)&sB[wbuf][row1 * 64 + (kc ^ ((row1 & 7) << 3))] =           \
              make_uint4(o[0], o[1], o[2], o[3]);                              \
      } }

#define GU_COMP(rbuf)                                                          \
    { _Pragma("unroll")                                                        \
      for (int kk = 0; kk < 2; ++kk) {                                         \
          const int col = ((kk * 32) + fk) ^ sw;                               \
          f16x8 af[4], bg[2], bu[2];                                           \
          _Pragma("unroll")                                                    \
          for (int i = 0; i < 4; ++i)                                          \
              af[i] = *(const f16x8*)&sAl[rbuf][(wm + i * 16 + frow) * 64 + col]; \
          bg[0] = *(const f16x8*)&sB1[rbuf][frow * 64 + col];                  \
          bg[1] = *(const f16x8*)&sB1[rbuf][(16 + frow) * 64 + col];           \
          bu[0] = *(const f16x8*)&sB2[rbuf][frow * 64 + col];                  \
          bu[1] = *(const f16x8*)&sB2[rbuf][(16 + frow) * 64 + col];           \
          _Pragma("unroll")                                                    \
          for (int mi = 0; mi < 4; ++mi)                                       \
              _Pragma("unroll")                                                \
              for (int ni = 0; ni < 2; ++ni) {                                 \
                  accG[mi][ni] = __builtin_amdgcn_mfma_f32_16x16x32_f16(af[mi], bg[ni], accG[mi][ni], 0, 0, 0); \
                  accU[mi][ni] = __builtin_amdgcn_mfma_f32_16x16x32_f16(af[mi], bu[ni], accU[mi][ni], 0, 0, 0); \
              } } }

// one barrier per K-step; DEQ(t+1) and COMP(t) share the scheduling window
#define GU_STEP(k0s, WBUF, RBUF, PW0, PW1, PZ0, PZ1, PZ2, PZ3, DOPF, VMS)      \
    { GU_GLDA((k0s) + BK, WBUF) SCHED0()                                       \
      GU_DEQ(WBUF, PW0, PW1, PZ0, PZ1, PZ2, PZ3)                               \
      if (DOPF) { GU_LD(PW0, PW1, PZ0, PZ1, PZ2, PZ3, (k0s) + 3 * BK) }        \
      GU_COMP(RBUF)                                                            \
      asm volatile("s_waitcnt vmcnt(" VMS ") lgkmcnt(0)" ::: "memory");        \
      __builtin_amdgcn_s_barrier();                                            \
      SCHED0() }

    // prologue: tile 0 in LDS, qw(1) in setA, qw(2) in setB
    GU_GLDA(0, 0)
    GU_LD(pwA0, pwA1, pzA0, pzA1, pzA2, pzA3, 0)
    asm volatile("s_waitcnt vmcnt(0)" ::: "memory"); SCHED0()
    GU_DEQ(0, pwA0, pwA1, pzA0, pzA1, pzA2, pzA3)
    GU_LD(pwA0, pwA1, pzA0, pzA1, pzA2, pzA3, BK)
    GU_LD(pwB0, pwB1, pzB0, pzB1, pzB2, pzB3, 2 * BK)
    asm volatile("s_waitcnt lgkmcnt(0)" ::: "memory");
    __builtin_amdgcn_s_barrier();
    SCHED0()

    for (int t = 0; t < 60; t += 2) {
        GU_STEP(t * BK,       1, 0, pwA0, pwA1, pzA0, pzA1, pzA2, pzA3, 1, "6")
        GU_STEP((t + 1) * BK, 0, 1, pwB0, pwB1, pzB0, pzB1, pzB2, pzB3, 1, "6")
    }
    GU_STEP(60 * BK, 1, 0, pwA0, pwA1, pzA0, pzA1, pzA2, pzA3, 1, "6")
    GU_STEP(61 * BK, 0, 1, pwB0, pwB1, pzB0, pzB1, pzB2, pzB3, 0, "0")
    GU_STEP(62 * BK, 1, 0, pwA0, pwA1, pzA0, pzA1, pzA2, pzA3, 0, "0")
    GU_COMP(1)   // tile 63

    // ---- epilogue: silu(gate)*up -> LDS -> coalesced f16 stores ----
    ushort* so = &sAl[0][0];   // 256 x 32 staging (buf 0 fully consumed)
    const int rb = (lane >> 4) * 4, cb = lane & 15;
#pragma unroll
    for (int mi = 0; mi < 4; ++mi)
#pragma unroll
        for (int ni = 0; ni < 2; ++ni) {
            f32x4 g = accG[mi][ni], u = accU[mi][ni];
            const int row = wm + mi * 16 + rb;
            const int colx = ni * 16 + cb;
#pragma unroll
            for (int r = 0; r < 4; ++r) {
                float gv = g[r];
                float hv = __fdividef(gv, 1.0f + __expf(-gv)) * u[r];
                __half hh = __float2half(hv);
                so[(row + r) * 32 + colx] = __builtin_bit_cast(ushort, hh);
            }
        }
    __syncthreads();
    {
        ushort* dst = hbuf + (size_t)(m0 + tid) * FFN + n0;
        const ushort* src = so + tid * 32;
#pragma unroll
        for (int i = 0; i < 4; ++i)
            *(uint4*)(dst + 8 * i) = *(const uint4*)(src + 8 * i);
    }
#undef GU_GLDA
#undef GU_LD
#undef GU_DEQ
#undef GU_COMP
#undef GU_STEP
}

// ---------------- GEMM B: out_partial = h @ w2^T (split-K = 2) ----------------
// BM=256, BN=32, BK=64, same single-barrier pipeline. NT = 112.

__global__ __launch_bounds__(256, 2)
void gemm_down(const ushort* __restrict__ hb, const uint32_t* __restrict__ qw2,
               const uint32_t* __restrict__ sz2, float* __restrict__ part) {
    __shared__ ushort sAl[2][256 * 64];   // 64 KB
    __shared__ ushort sBd[2][32 * 64];    // 8 KB

    const int tid = threadIdx.x;
    // 512 = 8 x 64 XCD swizzle
    const int idx = ((blockIdx.x & 7) * 64) + (blockIdx.x >> 3);
    const int mt = idx & 1, nt = (idx >> 1) & 127, sk = idx >> 8;
    const int m0 = mt * 256, n0 = nt * 32;
    const int kbeg = sk * (FFN / 2);

    const int lane = tid & 63, w = tid >> 6;
    const int wm = w * 64;
    const int frow = lane & 15, fk = (lane >> 4) * 8;
    const int sw = (frow & 7) << 3;

    const int qs = (lane & 7) ^ ((lane >> 3) & 7);
    const ushort* apS[8];
#pragma unroll
    for (int s = 0; s < 8; ++s) {
        int r = s * 32 + w * 8 + (lane >> 3);
        apS[s] = hb + (size_t)(m0 + r) * FFN + kbeg + qs * 8;
    }

    // B staging: 1 row x 8 k per thread (32 rows x 8 chunks = 256)
    const int r = tid >> 3;                 // 0..31
    const int kc = (tid & 7) * 8;
    const int g = ((nt & 1) * 32) + r;      // (n0 + r) % 64
    const uint32_t* qp = qw2 + (size_t)(n0 / 4 + (r >> 2)) * FFN + kbeg + kc;
    const uint32_t* zp = sz2 + (size_t)g * FFN + kbeg + kc;
    const uint32_t sh = 6u - 2u * (uint32_t)(r & 3);

    f32x4 acc[4][2];
#pragma unroll
    for (int i = 0; i < 4; ++i)
#pragma unroll
        for (int j = 0; j < 2; ++j) acc[i][j] = (f32x4){0.f, 0.f, 0.f, 0.f};

    uint4 pwA0, pwA1, pzA0, pzA1;
    uint4 pwB0, pwB1, pzB0, pzB1;

#define GD_GLDA(k0d, wbuf)                                                     \
    { _Pragma("unroll")                                                        \
      for (int s = 0; s < 8; ++s)                                              \
          gl_lds16(apS[s] + (k0d), &sAl[wbuf][(s * 256 + w * 64) * 8]); }

#define GD_LD(PW0, PW1, PZ0, PZ1, k0q)                                         \
    PW0 = *(const uint4*)(qp + (k0q));                                         \
    PW1 = *(const uint4*)(qp + (k0q) + 4);                                     \
    PZ0 = *(const uint4*)(zp + (k0q));                                         \
    PZ1 = *(const uint4*)(zp + (k0q) + 4);

#define GD_DEQ(wbuf, PW0, PW1, PZ0, PZ1)                                       \
    { const uint32_t wv[8] = {(PW0).x, (PW0).y, (PW0).z, (PW0).w,              \
                              (PW1).x, (PW1).y, (PW1).z, (PW1).w};             \
      const uint32_t sp[4] = {(PZ0).x, (PZ0).z, (PZ1).x, (PZ1).z};             \
      const uint32_t np[4] = {(PZ0).y, (PZ0).w, (PZ1).y, (PZ1).w};             \
      uint32_t o[4];                                                           \
      _Pragma("unroll")                                                        \
      for (int j = 0; j < 4; ++j)                                              \
          o[j] = deq2(wv[2*j], wv[2*j+1], sh, sp[j], np[j]);                   \
      *(uint4*)&sBd[wbuf][r * 64 + (kc ^ ((r & 7) << 3))] =                    \
          make_uint4(o[0], o[1], o[2], o[3]); }

#define GD_COMP(rbuf)                                                          \
    { _Pragma("unroll")                                                        \
      for (int kk = 0; kk < 2; ++kk) {                                         \
          const int col = ((kk * 32) + fk) ^ sw;                               \
          f16x8 af[4], bf[2];                                                  \
          _Pragma("unroll")                                                    \
          for (int i = 0; i < 4; ++i)                                          \
              af[i] = *(const f16x8*)&sAl[rbuf][(wm + i * 16 + frow) * 64 + col]; \
          bf[0] = *(const f16x8*)&sBd[rbuf][frow * 64 + col];                  \
          bf[1] = *(const f16x8*)&sBd[rbuf][(16 + frow) * 64 + col];           \
          _Pragma("unroll")                                                    \
          for (int mi = 0; mi < 4; ++mi)                                       \
              _Pragma("unroll")                                                \
              for (int ni = 0; ni < 2; ++ni)                                   \
                  acc[mi][ni] = __builtin_amdgcn_mfma_f32_16x16x32_f16(af[mi], bf[ni], acc[mi][ni], 0, 0, 0); \
      } }

#define GD_STEP(k0s, WBUF, RBUF, PW0, PW1, PZ0, PZ1, DOPF, VMS)                \
    { GD_GLDA((k0s) + BK, WBUF) SCHED0()                                       \
      GD_DEQ(WBUF, PW0, PW1, PZ0, PZ1)                                         \
      if (DOPF) { GD_LD(PW0, PW1, PZ0, PZ1, (k0s) + 3 * BK) }                  \
      GD_COMP(RBUF)                                                            \
      asm volatile("s_waitcnt vmcnt(" VMS ") lgkmcnt(0)" ::: "memory");        \
      __builtin_amdgcn_s_barrier();                                            \
      SCHED0() }

    GD_GLDA(0, 0)
    GD_LD(pwA0, pwA1, pzA0, pzA1, 0)
    asm volatile("s_waitcnt vmcnt(0)" ::: "memory"); SCHED0()
    GD_DEQ(0, pwA0, pwA1, pzA0, pzA1)
    GD_LD(pwA0, pwA1, pzA0, pzA1, BK)
    GD_LD(pwB0, pwB1, pzB0, pzB1, 2 * BK)
    asm volatile("s_waitcnt lgkmcnt(0)" ::: "memory");
    __builtin_amdgcn_s_barrier();
    SCHED0()

    for (int t = 0; t < 108; t += 2) {
        GD_STEP(t * BK,       1, 0, pwA0, pwA1, pzA0, pzA1, 1, "4")
        GD_STEP((t + 1) * BK, 0, 1, pwB0, pwB1, pzB0, pzB1, 1, "4")
    }
    GD_STEP(108 * BK, 1, 0, pwA0, pwA1, pzA0, pzA1, 1, "4")
    GD_STEP(109 * BK, 0, 1, pwB0, pwB1, pzB0, pzB1, 0, "0")
    GD_STEP(110 * BK, 1, 0, pwA0, pwA1, pzA0, pzA1, 0, "0")
    GD_COMP(1)   // tile 111

    float* pp = part + (size_t)sk * MDIM * HIDDEN;
    const int rb = (lane >> 4) * 4, cb = lane & 15;
#pragma unroll
    for (int mi = 0; mi < 4; ++mi)
#pragma unroll
        for (int ni = 0; ni < 2; ++ni) {
            f32x4 a = acc[mi][ni];
            const int mm = m0 + wm + mi * 16 + rb;
            const int nn = n0 + ni * 16 + cb;
#pragma unroll
            for (int rr = 0; rr < 4; ++rr) pp[(size_t)(mm + rr) * HIDDEN + nn] = a[rr];
        }
#undef GD_GLDA
#undef GD_LD
#undef GD_DEQ
#undef GD_COMP
#undef GD_STEP
}

// ---------------- reduce split-K partials ----------------

__global__ void reduce_out(const float* __restrict__ part, float* __restrict__ out) {
    int i = blockIdx.x * blockDim.x + threadIdx.x;
    const int Q = MDIM * HIDDEN / 4;
    float4 a = ((const float4*)part)[i];
    float4 b = ((const float4*)part)[i + Q];
    float4 o;
    o.x = a.x + b.x; o.y = a.y + b.y; o.z = a.z + b.z; o.w = a.w + b.w;
    ((float4*)out)[i] = o;
}

// ---------------- launch ----------------

extern "C" void kernel_launch(void* const* d_in, const int* in_sizes, int n_in,
                              void* d_out, int out_size, void* d_ws, size_t ws_size,
                              hipStream_t stream) {
    (void)in_sizes; (void)n_in; (void)out_size; (void)ws_size;

    const float* x  = (const float*)d_in[0];
    const uint32_t* qw1 = (const uint32_t*)d_in[1];
    const float* s1 = (const float*)d_in[2];
    const float* z1 = (const float*)d_in[3];
    const uint32_t* qw3 = (const uint32_t*)d_in[4];
    const float* s3 = (const float*)d_in[5];
    const float* z3 = (const float*)d_in[6];
    const uint32_t* qw2 = (const uint32_t*)d_in[7];
    const float* s2 = (const float*)d_in[8];
    const float* z2 = (const float*)d_in[9];
    float* out = (float*)d_out;

    // ws: xb 4.19M | sz1 3.67M | sz3 3.67M | sz2 3.67M | h(f16) 14.68M | part 16.78M
    char* ws = (char*)d_ws;
    ushort*   xb   = (ushort*)ws;
    uint32_t* szp1 = (uint32_t*)(ws + (size_t)MDIM * HIDDEN * 2);
    uint32_t* szp3 = szp1 + (size_t)G1 * HIDDEN;
    uint32_t* szp2 = szp3 + (size_t)G1 * HIDDEN;
    ushort*   hbuf = (ushort*)(szp2 + (size_t)G2 * FFN);
    float*    part = (float*)((char*)hbuf + (size_t)MDIM * FFN * 2);

    cvt_x_kernel<<<(MDIM * HIDDEN / 4) / 256, 256, 0, stream>>>(x, xb);
    build_sz_kernel<<<(G1 * HIDDEN / 2) / 256, 256, 0, stream>>>(s1, z1, szp1);
    build_sz_kernel<<<(G1 * HIDDEN / 2) / 256, 256, 0, stream>>>(s3, z3, szp3);
    build_sz_kernel<<<(G2 * FFN / 2) / 256, 256, 0, stream>>>(s2, z2, szp2);

    gemm_gateup<<<(FFN / 32) * (MDIM / 256), 256, 0, stream>>>(xb, qw1, szp1, qw3, szp3, hbuf);
    gemm_down<<<2 * (MDIM / 256) * (HIDDEN / 32), 256, 0, stream>>>(hbuf, qw2, szp2, part);
    reduce_out<<<(MDIM * HIDDEN / 4) / 256, 256, 0, stream>>>(part, out);
}